// Round 1
// baseline (1005.734 us; speedup 1.0000x reference)
//
#include <hip/hip_runtime.h>
#include <hip/hip_bf16.h>

#define Cc 128
#define Hh 4
#define Dd 32
#define DPHI 64
#define Ll 2
#define Tt 2
#define Rr 2

typedef __hip_bfloat16 bf16;

__device__ __forceinline__ float gelu_tanh(float x) {
  float inner = 0.7978845608028654f * (x + 0.044715f * x * x * x);
  return 0.5f * x * (1.0f + tanhf(inner));
}

// ---------------- CSR build ----------------
__global__ void hist_kernel(const int* __restrict__ src, const int* __restrict__ dst,
                            int E_, int* cntu, int* cntm) {
  int e = blockIdx.x * 256 + threadIdx.x;
  if (e < E_) {
    atomicAdd(&cntm[dst[e]], 1);
    atomicAdd(&cntu[src[e]], 1);
  }
}

__global__ __launch_bounds__(1024) void scan_kernel(const int* __restrict__ cnt,
                                                    int* __restrict__ rowptr, int n) {
  __shared__ int sdata[1024];
  __shared__ int carry_s;
  if (threadIdx.x == 0) { carry_s = 0; rowptr[0] = 0; }
  __syncthreads();
  for (int base = 0; base < n; base += 1024) {
    int i = base + (int)threadIdx.x;
    int v = (i < n) ? cnt[i] : 0;
    sdata[threadIdx.x] = v;
    __syncthreads();
    for (int offd = 1; offd < 1024; offd <<= 1) {
      int t = (threadIdx.x >= (unsigned)offd) ? sdata[threadIdx.x - offd] : 0;
      __syncthreads();
      sdata[threadIdx.x] += t;
      __syncthreads();
    }
    int carry = carry_s;
    if (i < n) rowptr[i + 1] = carry + sdata[threadIdx.x];
    __syncthreads();
    if (threadIdx.x == 0) carry_s = carry + sdata[1023];
    __syncthreads();
  }
}

__global__ void scatter_kernel(const int* __restrict__ src, const int* __restrict__ dst, int E_,
                               const int* __restrict__ rpm, const int* __restrict__ rpu,
                               int* cntm, int* cntu, int* srcm, int* srcu) {
  int e = blockIdx.x * 256 + threadIdx.x;
  if (e < E_) {
    int s = src[e], d = dst[e];
    int pm = rpm[d] + atomicAdd(&cntm[d], 1);
    srcm[pm] = s;
    int pu = rpu[s] + atomicAdd(&cntu[s], 1);
    srcu[pu] = d;
  }
}

// ---------------- weight prep: WK' = kw @ a_rel (scaled by p_rel/sqrtD), WV' = vw @ m_rel ----
__global__ __launch_bounds__(256) void prep_weights(
    const float* __restrict__ kw, const float* __restrict__ kb,
    const float* __restrict__ vw, const float* __restrict__ vb,
    const float* __restrict__ a_rel, const float* __restrict__ m_rel,
    const float* __restrict__ p_rel,
    float* __restrict__ WKp, float* __restrict__ bKp,
    float* __restrict__ WVp, float* __restrict__ bVp) {
  int lt = blockIdx.x;   // l*2 + t
  int mat = blockIdx.y;  // 0 = K, 1 = V
  int l = lt >> 1, t = lt & 1;
  int r = t;  // source type index == edge type index
  const float* Wi = (mat ? vw : kw) + (size_t)lt * Cc * Cc;
  const float* bi = (mat ? vb : kb) + (size_t)lt * Cc;
  const float* A  = (mat ? m_rel : a_rel) + ((size_t)l * Rr + r) * Hh * Dd * Dd;
  float* Wo = (mat ? WVp : WKp) + (size_t)lt * Cc * Cc;
  float* bo = (mat ? bVp : bKp) + (size_t)lt * Cc;
  const float inv_sqrt_d = 0.17677669529663687f;  // 1/sqrt(32)
  for (int idx = threadIdx.x; idx < Cc * Cc; idx += 256) {
    int k = idx >> 7, cc = idx & 127;
    int h = cc >> 5, e = cc & 31;
    const float* Ah = A + h * Dd * Dd;
    float s = 0.f;
    for (int dd = 0; dd < Dd; ++dd) s += Wi[k * Cc + h * Dd + dd] * Ah[dd * Dd + e];
    float scale = mat ? 1.0f : p_rel[((size_t)l * Rr + r) * Hh + h] * inv_sqrt_d;
    Wo[idx] = s * scale;
  }
  if (threadIdx.x < Cc) {
    int cc = threadIdx.x, h = cc >> 5, e = cc & 31;
    const float* Ah = A + h * Dd * Dd;
    float s = 0.f;
    for (int dd = 0; dd < Dd; ++dd) s += bi[h * Dd + dd] * Ah[dd * Dd + e];
    float scale = mat ? 1.0f : p_rel[((size_t)l * Rr + r) * Hh + h] * inv_sqrt_d;
    bo[cc] = s * scale;
  }
}

// ---------------- init: x_user = user_emb; x_movie = movie_emb + phi@meta_w + meta_b ----
__global__ void copy_user(const float* __restrict__ ue, float* __restrict__ xout, int n) {
  int i = blockIdx.x * 256 + threadIdx.x;
  if (i < n) xout[i] = ue[i];
}

__global__ __launch_bounds__(128) void movie_init(
    const float* __restrict__ me, const float* __restrict__ phi,
    const float* __restrict__ mw, const float* __restrict__ mb,
    float* __restrict__ xout, int NM) {
  int m = blockIdx.x, c = threadIdx.x;
  float s = me[(size_t)m * Cc + c] + mb[c];
  const float* ph = phi + (size_t)m * DPHI;
  for (int j = 0; j < DPHI; ++j) s += ph[j] * mw[j * Cc + c];
  xout[(size_t)m * Cc + c] = s;
}

// ---------------- GEMM [M x 128] @ [128 x 128] ----------------
// MODE 0: out_bf16 = X @ W + bias            (projection)
// MODE 1: out_f32  = g*(gelu(X) @ W + bias) + (1-g)*out_f32   (output proj + skip)
template <int MODE>
__global__ __launch_bounds__(256) void gemm128(
    int M, const float* __restrict__ X, const float* __restrict__ W,
    const float* __restrict__ bias, bf16* __restrict__ outb,
    float* __restrict__ outf, const float* __restrict__ skipp) {
  __shared__ float Xs[64 * 132];  // stride 132: 2-way-max bank aliasing on reads
  __shared__ float Ws[128 * 64];
  int r0 = blockIdx.x * 64;
  int c0 = blockIdx.y * 64;
  int tid = threadIdx.x;
  // stage X tile (64 rows x 128 k), optional gelu
  {
    int lr = tid >> 5;          // 0..7
    int kc = (tid & 31) * 4;    // 0..124
#pragma unroll
    for (int p = 0; p < 8; ++p) {
      int row = r0 + p * 8 + lr;
      float4 v = make_float4(0.f, 0.f, 0.f, 0.f);
      if (row < M) v = *(const float4*)&X[(size_t)row * Cc + kc];
      if (MODE == 1) {
        v.x = gelu_tanh(v.x); v.y = gelu_tanh(v.y);
        v.z = gelu_tanh(v.z); v.w = gelu_tanh(v.w);
      }
      *(float4*)&Xs[(p * 8 + lr) * 132 + kc] = v;
    }
  }
  // stage W tile (128 k x 64 cols)
  {
    int lk = tid >> 4;          // 0..15
    int cc = (tid & 15) * 4;    // 0..60
#pragma unroll
    for (int p = 0; p < 8; ++p) {
      int k = p * 16 + lk;
      float4 v = *(const float4*)&W[k * Cc + c0 + cc];
      *(float4*)&Ws[k * 64 + cc] = v;
    }
  }
  __syncthreads();
  int tx = tid & 15, ty = tid >> 4;
  float acc[4][4] = {};
#pragma unroll 4
  for (int k = 0; k < 128; ++k) {
    float4 wv = *(const float4*)&Ws[k * 64 + tx * 4];
#pragma unroll
    for (int i = 0; i < 4; ++i) {
      float xv = Xs[(ty * 4 + i) * 132 + k];
      acc[i][0] += xv * wv.x;
      acc[i][1] += xv * wv.y;
      acc[i][2] += xv * wv.z;
      acc[i][3] += xv * wv.w;
    }
  }
  float g = 0.f;
  if (MODE == 1) g = 1.0f / (1.0f + __expf(-skipp[0]));
#pragma unroll
  for (int i = 0; i < 4; ++i) {
    int row = r0 + ty * 4 + i;
    if (row >= M) continue;
#pragma unroll
    for (int j = 0; j < 4; ++j) {
      int col = c0 + tx * 4 + j;
      float v = acc[i][j] + bias[col];
      if (MODE == 0) {
        outb[(size_t)row * Cc + col] = __float2bfloat16(v);
      } else {
        float old = outf[(size_t)row * Cc + col];
        outf[(size_t)row * Cc + col] = g * v + (1.f - g) * old;
      }
    }
  }
}

// ---------------- fused per-destination softmax + aggregation ----------------
// block = 128 threads (one per channel), one block per dst node.
__global__ __launch_bounds__(128) void agg_kernel(
    const int* __restrict__ rowptr, const int* __restrict__ srclist,
    const bf16* __restrict__ Qdst, const bf16* __restrict__ KEsrc,
    const bf16* __restrict__ VEsrc, float* __restrict__ AGGdst) {
  int d = blockIdx.x;
  int c = threadIdx.x;
  float qc = __bfloat162float(Qdst[(size_t)d * Cc + c]);
  int beg = rowptr[d], end = rowptr[d + 1];
  float denom = 0.f, acc = 0.f;
  for (int e = beg; e < end; ++e) {
    int s = srclist[e];
    float p = qc * __bfloat162float(KEsrc[(size_t)s * Cc + c]);
    p += __shfl_xor(p, 16, 32);
    p += __shfl_xor(p, 8, 32);
    p += __shfl_xor(p, 4, 32);
    p += __shfl_xor(p, 2, 32);
    p += __shfl_xor(p, 1, 32);
    float w = __expf(p);  // logits tiny; softmax shift-invariant so no max pass
    denom += w;
    acc += w * __bfloat162float(VEsrc[(size_t)s * Cc + c]);
  }
  AGGdst[(size_t)d * Cc + c] = acc / (denom + 1e-16f);
}

// ---------------- launch ----------------
extern "C" void kernel_launch(void* const* d_in, const int* in_sizes, int n_in,
                              void* d_out, int out_size, void* d_ws, size_t ws_size,
                              hipStream_t stream) {
  const float* user_emb = (const float*)d_in[0];
  const float* movie_emb = (const float*)d_in[1];
  const float* phi = (const float*)d_in[2];
  const float* meta_w = (const float*)d_in[3];
  const float* meta_b = (const float*)d_in[4];
  const float* kw = (const float*)d_in[5];
  const float* kb = (const float*)d_in[6];
  const float* qw = (const float*)d_in[7];
  const float* qb = (const float*)d_in[8];
  const float* vw = (const float*)d_in[9];
  const float* vb = (const float*)d_in[10];
  const float* a_rel = (const float*)d_in[11];
  const float* m_rel = (const float*)d_in[12];
  const float* p_rel = (const float*)d_in[13];
  const float* ow = (const float*)d_in[14];
  const float* ob = (const float*)d_in[15];
  const float* skip = (const float*)d_in[16];
  const int* eidx = (const int*)d_in[17];

  int NU = in_sizes[0] / Cc;
  int NM = in_sizes[1] / Cc;
  int E_ = in_sizes[17] / 2;
  int NT = NU + NM;
  const int* esrc = eidx;        // user ids (row 0)
  const int* edst = eidx + E_;   // movie ids (row 1)

  char* ws = (char*)d_ws;
  size_t off = 0;
  auto alloc = [&](size_t bytes) -> char* {
    char* p = ws + off;
    off = (off + bytes + 255) & ~(size_t)255;
    return p;
  };
  bf16* Qb   = (bf16*)alloc((size_t)NT * Cc * 2);
  bf16* KEb  = (bf16*)alloc((size_t)NT * Cc * 2);
  bf16* VEb  = (bf16*)alloc((size_t)NT * Cc * 2);
  float* AGG = (float*)alloc((size_t)NT * Cc * 4);
  int* rpm   = (int*)alloc((size_t)(NM + 1) * 4);
  int* rpu   = (int*)alloc((size_t)(NU + 1) * 4);
  int* srcm  = (int*)alloc((size_t)E_ * 4);
  int* srcu  = (int*)alloc((size_t)E_ * 4);
  int* cntm  = (int*)alloc((size_t)NM * 4);
  int* cntu  = (int*)alloc((size_t)NU * 4);
  float* WKp = (float*)alloc((size_t)Ll * Tt * Cc * Cc * 4);
  float* WVp = (float*)alloc((size_t)Ll * Tt * Cc * Cc * 4);
  float* bKp = (float*)alloc((size_t)Ll * Tt * Cc * 4);
  float* bVp = (float*)alloc((size_t)Ll * Tt * Cc * 4);
  float* xout = (float*)d_out;  // [NT][C]: user rows then movie rows

  // CSR build (both directions)
  hipMemsetAsync(cntm, 0, (size_t)NM * 4, stream);
  hipMemsetAsync(cntu, 0, (size_t)NU * 4, stream);
  hist_kernel<<<(E_ + 255) / 256, 256, 0, stream>>>(esrc, edst, E_, cntu, cntm);
  scan_kernel<<<1, 1024, 0, stream>>>(cntm, rpm, NM);
  scan_kernel<<<1, 1024, 0, stream>>>(cntu, rpu, NU);
  hipMemsetAsync(cntm, 0, (size_t)NM * 4, stream);
  hipMemsetAsync(cntu, 0, (size_t)NU * 4, stream);
  scatter_kernel<<<(E_ + 255) / 256, 256, 0, stream>>>(esrc, edst, E_, rpm, rpu,
                                                       cntm, cntu, srcm, srcu);

  prep_weights<<<dim3(4, 2), 256, 0, stream>>>(kw, kb, vw, vb, a_rel, m_rel, p_rel,
                                               WKp, bKp, WVp, bVp);

  copy_user<<<(NU * Cc + 255) / 256, 256, 0, stream>>>(user_emb, xout, NU * Cc);
  movie_init<<<NM, 128, 0, stream>>>(movie_emb, phi, meta_w, meta_b,
                                     xout + (size_t)NU * Cc, NM);

  for (int l = 0; l < Ll; ++l) {
    for (int t = 0; t < Tt; ++t) {
      int n = t ? NM : NU;
      size_t roff = t ? (size_t)NU * Cc : 0;
      const float* xin = xout + roff;
      int lt = l * Tt + t;
      dim3 grid((n + 63) / 64, 2);
      gemm128<0><<<grid, 256, 0, stream>>>(n, xin, qw + (size_t)lt * Cc * Cc,
                                           qb + (size_t)lt * Cc, Qb + roff, nullptr, nullptr);
      gemm128<0><<<grid, 256, 0, stream>>>(n, xin, WKp + (size_t)lt * Cc * Cc,
                                           bKp + (size_t)lt * Cc, KEb + roff, nullptr, nullptr);
      gemm128<0><<<grid, 256, 0, stream>>>(n, xin, WVp + (size_t)lt * Cc * Cc,
                                           bVp + (size_t)lt * Cc, VEb + roff, nullptr, nullptr);
    }
    // r=0: user -> movie (dst = movies)
    agg_kernel<<<NM, 128, 0, stream>>>(rpm, srcm, Qb + (size_t)NU * Cc, KEb, VEb,
                                       AGG + (size_t)NU * Cc);
    // r=1: movie -> user (dst = users)
    agg_kernel<<<NU, 128, 0, stream>>>(rpu, srcu, Qb, KEb + (size_t)NU * Cc,
                                       VEb + (size_t)NU * Cc, AGG);
    for (int t = 0; t < Tt; ++t) {
      int n = t ? NM : NU;
      size_t roff = t ? (size_t)NU * Cc : 0;
      int lt = l * Tt + t;
      dim3 grid((n + 63) / 64, 2);
      gemm128<1><<<grid, 256, 0, stream>>>(n, AGG + roff, ow + (size_t)lt * Cc * Cc,
                                           ob + (size_t)lt * Cc, nullptr, xout + roff,
                                           skip + lt);
    }
  }
}

// Round 2
// 781.698 us; speedup vs baseline: 1.2866x; 1.2866x over previous
//
#include <hip/hip_runtime.h>
#include <hip/hip_bf16.h>

#define Cc 128
#define Hh 4
#define Dd 32
#define DPHI2 64
#define Ll 2
#define Tt 2
#define Rr 2

typedef __hip_bfloat16 bf16;
using short8 = __attribute__((ext_vector_type(8))) short;
using f32x4 = __attribute__((ext_vector_type(4))) float;

__device__ __forceinline__ unsigned short f2bf(float f) {
  union { float f; unsigned u; } v; v.f = f;
  unsigned r = v.u + 0x7fff + ((v.u >> 16) & 1);
  return (unsigned short)(r >> 16);
}
__device__ __forceinline__ float bf2f(unsigned short b) {
  union { unsigned u; float f; } v; v.u = ((unsigned)b) << 16;
  return v.f;
}
__device__ __forceinline__ float gelu_tanh(float x) {
  float u = 0.7978845608028654f * (x + 0.044715f * x * x * x);
  float t = 1.f - 2.f / (__expf(2.f * u) + 1.f);  // tanh(u)
  return 0.5f * x * (1.f + t);
}

// ---------------- CSR build ----------------
__global__ void hist_kernel(const int* __restrict__ src, const int* __restrict__ dst,
                            int E_, int* cntu, int* cntm) {
  int e = blockIdx.x * 256 + threadIdx.x;
  if (e < E_) {
    atomicAdd(&cntm[dst[e]], 1);
    atomicAdd(&cntu[src[e]], 1);
  }
}

__global__ __launch_bounds__(1024) void scan_kernel(const int* __restrict__ cnt,
                                                    int* __restrict__ rowptr, int n) {
  __shared__ int sdata[1024];
  __shared__ int carry_s;
  if (threadIdx.x == 0) { carry_s = 0; rowptr[0] = 0; }
  __syncthreads();
  for (int base = 0; base < n; base += 4096) {
    int i0 = base + (int)threadIdx.x * 4;
    int a0 = (i0 + 0 < n) ? cnt[i0 + 0] : 0;
    int a1 = (i0 + 1 < n) ? cnt[i0 + 1] : 0;
    int a2 = (i0 + 2 < n) ? cnt[i0 + 2] : 0;
    int a3 = (i0 + 3 < n) ? cnt[i0 + 3] : 0;
    int s = a0 + a1 + a2 + a3;
    sdata[threadIdx.x] = s;
    __syncthreads();
    for (int off = 1; off < 1024; off <<= 1) {
      int t = (threadIdx.x >= (unsigned)off) ? sdata[threadIdx.x - off] : 0;
      __syncthreads();
      sdata[threadIdx.x] += t;
      __syncthreads();
    }
    int incl = sdata[threadIdx.x];
    int run = carry_s + incl - s;
    if (i0 + 0 < n) rowptr[i0 + 1] = run + a0;
    if (i0 + 1 < n) rowptr[i0 + 2] = run + a0 + a1;
    if (i0 + 2 < n) rowptr[i0 + 3] = run + a0 + a1 + a2;
    if (i0 + 3 < n) rowptr[i0 + 4] = run + s;
    __syncthreads();
    if (threadIdx.x == 1023) carry_s = carry_s + incl;
    __syncthreads();
  }
}

__global__ void scatter_kernel(const int* __restrict__ src, const int* __restrict__ dst, int E_,
                               const int* __restrict__ rpm, const int* __restrict__ rpu,
                               int* cntm, int* cntu, int* srcm, int* srcu, int NU_) {
  int e = blockIdx.x * 256 + threadIdx.x;
  if (e < E_) {
    int s = src[e], d = dst[e];
    int pm = rpm[d] + atomicAdd(&cntm[d], 1);
    srcm[pm] = s;                 // user global row
    int pu = rpu[s] + atomicAdd(&cntu[s], 1);
    srcu[pu] = NU_ + d;           // movie global row
  }
}

// ---------------- weight prep ----------------
// WT[lt][384][128] bf16 (pre-transposed fused [WQ | kw@a_rel*scale | vw@m_rel]),
// bQKV[lt][384] f32, OWT[lt][128][128] bf16 (ow^T), bO[lt][128] f32.
__global__ __launch_bounds__(128) void prep_weights(
    const float* __restrict__ kw, const float* __restrict__ kb,
    const float* __restrict__ qw, const float* __restrict__ qb,
    const float* __restrict__ vw, const float* __restrict__ vb,
    const float* __restrict__ a_rel, const float* __restrict__ m_rel,
    const float* __restrict__ p_rel, const float* __restrict__ ow,
    const float* __restrict__ ob,
    unsigned short* __restrict__ WT, float* __restrict__ bQKV,
    unsigned short* __restrict__ OWT, float* __restrict__ bO) {
  int g = blockIdx.x;   // 0..511
  int lt = blockIdx.y;  // 0..3
  int l = lt >> 1, t = lt & 1, r = t;
  int k = threadIdx.x;
  const float inv_sqrt_d = 0.17677669529663687f;
  float val, bval;
  if (g < 128) {
    val = qw[((size_t)lt * Cc + k) * Cc + g];
    bval = qb[(size_t)lt * Cc + g];
  } else if (g < 384) {
    int isV = (g >= 256);
    int n = g - (isV ? 256 : 128);
    int h = n >> 5, e = n & 31;
    const float* W = (isV ? vw : kw) + (size_t)lt * Cc * Cc;
    const float* bb = (isV ? vb : kb) + (size_t)lt * Cc;
    const float* Ah = (isV ? m_rel : a_rel) + (((size_t)l * Rr + r) * Hh + h) * Dd * Dd;
    float s = 0.f, sb = 0.f;
    for (int d = 0; d < Dd; ++d) {
      float ae = Ah[d * Dd + e];
      s += W[(size_t)k * Cc + h * Dd + d] * ae;
      sb += bb[h * Dd + d] * ae;
    }
    float scale = isV ? 1.f : p_rel[((size_t)l * Rr + r) * Hh + h] * inv_sqrt_d;
    val = s * scale;
    bval = sb * scale;
  } else {
    int n = g - 384;
    val = ow[((size_t)lt * Cc + k) * Cc + n];
    bval = ob[(size_t)lt * Cc + n];
  }
  if (g < 384) {
    WT[((size_t)lt * 384 + g) * Cc + k] = f2bf(val);
    if (k == 0) bQKV[(size_t)lt * 384 + g] = bval;
  } else {
    OWT[((size_t)lt * Cc + (g - 384)) * Cc + k] = f2bf(val);
    if (k == 0) bO[(size_t)lt * Cc + (g - 384)] = bval;
  }
}

// ---------------- init: xout (f32) + Xb (bf16) ----------------
__global__ void init_kernel(const float* __restrict__ ue, const float* __restrict__ me,
                            const float* __restrict__ phi, const float* __restrict__ mw,
                            const float* __restrict__ mb,
                            float* __restrict__ xout, unsigned short* __restrict__ Xb,
                            int NU_, int NM_) {
  int i = blockIdx.x * 256 + threadIdx.x;
  int totalU = NU_ * Cc;
  if (i < totalU) {
    float v = ue[i];
    xout[i] = v;
    Xb[i] = f2bf(v);
  } else {
    int j = i - totalU;
    if (j >= NM_ * Cc) return;
    int m = j >> 7, c = j & 127;
    float s = me[j] + mb[c];
    const float* ph = phi + (size_t)m * DPHI2;
    for (int d = 0; d < DPHI2; ++d) s += ph[d] * mw[d * Cc + c];
    xout[i] = s;
    Xb[i] = f2bf(s);
  }
}

// ---------------- register-only MFMA GEMM [M x 128] @ [128 x 64*NCH] ----------------
// MODE 0: fused QKV proj, writes Qb (cols 0-127) and KVb (cols 128-383 -> row stride 256)
// MODE 1: out proj + skip-mix, writes xout (f32) and Xb (bf16)
template <int NCH, int MODE>
__global__ __launch_bounds__(256, 2) void mfma_gemm(
    int M, const bf16* __restrict__ A, const bf16* __restrict__ BT,
    const float* __restrict__ bias,
    unsigned short* __restrict__ Qb, unsigned short* __restrict__ KVb,
    float* __restrict__ xout, unsigned short* __restrict__ Xb,
    const float* __restrict__ skipp) {
  int tid = threadIdx.x;
  int wid = tid >> 6, lane = tid & 63;
  int row0 = blockIdx.x * 256 + wid * 64;
  if (row0 >= M) return;
  int lr = lane & 15, lk8 = (lane >> 4) * 8;
  short8 a[4][4];
#pragma unroll
  for (int mt = 0; mt < 4; ++mt) {
    int r = row0 + mt * 16 + lr;
    const bf16* ap = A + (size_t)r * Cc + lk8;
#pragma unroll
    for (int kk = 0; kk < 4; ++kk) {
      short8 v = {};
      if (r < M) v = *(const short8*)(ap + kk * 32);
      a[mt][kk] = v;
    }
  }
  float g = 0.f;
  if (MODE == 1) g = 1.f / (1.f + __expf(-skipp[0]));
#pragma unroll
  for (int ch = 0; ch < NCH; ++ch) {
    short8 b[4][4];
#pragma unroll
    for (int nt = 0; nt < 4; ++nt) {
      const bf16* bp = BT + (size_t)(ch * 64 + nt * 16 + lr) * Cc + lk8;
#pragma unroll
      for (int kk = 0; kk < 4; ++kk) b[nt][kk] = *(const short8*)(bp + kk * 32);
    }
    f32x4 acc[4][4];
#pragma unroll
    for (int mt = 0; mt < 4; ++mt)
#pragma unroll
      for (int nt = 0; nt < 4; ++nt) acc[mt][nt] = (f32x4){0.f, 0.f, 0.f, 0.f};
#pragma unroll
    for (int kk = 0; kk < 4; ++kk)
#pragma unroll
      for (int mt = 0; mt < 4; ++mt)
#pragma unroll
        for (int nt = 0; nt < 4; ++nt)
          acc[mt][nt] = __builtin_amdgcn_mfma_f32_16x16x32_bf16(
              a[mt][kk], b[nt][kk], acc[mt][nt], 0, 0, 0);
#pragma unroll
    for (int nt = 0; nt < 4; ++nt) {
      int gcol = ch * 64 + nt * 16 + lr;
      float bs = bias[gcol];
#pragma unroll
      for (int mt = 0; mt < 4; ++mt) {
#pragma unroll
        for (int j = 0; j < 4; ++j) {
          int r = row0 + mt * 16 + (lane >> 4) * 4 + j;
          if (r >= M) continue;
          float val = acc[mt][nt][j] + bs;
          if (MODE == 0) {
            if (gcol < Cc)
              Qb[(size_t)r * Cc + gcol] = f2bf(val);
            else
              KVb[(size_t)r * 256 + (gcol - Cc)] = f2bf(val);
          } else {
            size_t o = (size_t)r * Cc + gcol;
            float nv = g * val + (1.f - g) * xout[o];
            xout[o] = nv;
            Xb[o] = f2bf(nv);
          }
        }
      }
    }
  }
}

// ---------------- fused softmax+agg: 1 wave per dst, gelu epilogue ----------------
// KV rows: [KE(128) | VE(128)] bf16 (512B). Lane L loads 4 channels at 4*L.
// Lanes 0-31: KE (dot partials); lanes 32-63: VE (accumulate). Head h = channels
// 32h..32h+31 = lanes 8h..8h+7 -> 3 shfl_xor reduce + 1 shfl broadcast.
__global__ __launch_bounds__(256) void agg_kernel(
    const int* __restrict__ rpm, const int* __restrict__ srcm,
    const int* __restrict__ rpu, const int* __restrict__ srcu,
    const unsigned short* __restrict__ Qb, const unsigned short* __restrict__ KVb,
    unsigned short* __restrict__ AGGb, int NM_, int NU_) {
  int wid = threadIdx.x >> 6, lane = threadIdx.x & 63;
  int W = blockIdx.x * 4 + wid;
  int dnode, beg, end;
  const int* list;
  if (W < NM_) {
    dnode = NU_ + W; beg = rpm[W]; end = rpm[W + 1]; list = srcm;
  } else {
    int u = W - NM_;
    if (u >= NU_) return;
    dnode = u; beg = rpu[u]; end = rpu[u + 1]; list = srcu;
  }
  int l31 = lane & 31;
  const unsigned short* qrow = Qb + (size_t)dnode * Cc + l31 * 4;
  float q0 = bf2f(qrow[0]), q1 = bf2f(qrow[1]), q2 = bf2f(qrow[2]), q3 = bf2f(qrow[3]);
  float acc0 = 0.f, acc1 = 0.f, acc2 = 0.f, acc3 = 0.f, denom = 0.f;
  int srcl = l31 & 56;
  int e = beg;
  for (; e + 1 < end; e += 2) {
    int s0 = list[e], s1 = list[e + 1];
    uint2 ra = *(const uint2*)(KVb + (size_t)s0 * 256 + lane * 4);
    uint2 rb = *(const uint2*)(KVb + (size_t)s1 * 256 + lane * 4);
    float a0 = bf2f((unsigned short)(ra.x & 0xffff));
    float a1 = bf2f((unsigned short)(ra.x >> 16));
    float a2 = bf2f((unsigned short)(ra.y & 0xffff));
    float a3 = bf2f((unsigned short)(ra.y >> 16));
    float b0 = bf2f((unsigned short)(rb.x & 0xffff));
    float b1 = bf2f((unsigned short)(rb.x >> 16));
    float b2 = bf2f((unsigned short)(rb.y & 0xffff));
    float b3 = bf2f((unsigned short)(rb.y >> 16));
    float pa = q0 * a0 + q1 * a1 + q2 * a2 + q3 * a3;
    float pb = q0 * b0 + q1 * b1 + q2 * b2 + q3 * b3;
    pa += __shfl_xor(pa, 1, 64); pb += __shfl_xor(pb, 1, 64);
    pa += __shfl_xor(pa, 2, 64); pb += __shfl_xor(pb, 2, 64);
    pa += __shfl_xor(pa, 4, 64); pb += __shfl_xor(pb, 4, 64);
    float wa = __expf(__shfl(pa, srcl, 64));
    float wb = __expf(__shfl(pb, srcl, 64));
    denom += wa + wb;
    acc0 += wa * a0 + wb * b0;
    acc1 += wa * a1 + wb * b1;
    acc2 += wa * a2 + wb * b2;
    acc3 += wa * a3 + wb * b3;
  }
  if (e < end) {
    int s0 = list[e];
    uint2 ra = *(const uint2*)(KVb + (size_t)s0 * 256 + lane * 4);
    float a0 = bf2f((unsigned short)(ra.x & 0xffff));
    float a1 = bf2f((unsigned short)(ra.x >> 16));
    float a2 = bf2f((unsigned short)(ra.y & 0xffff));
    float a3 = bf2f((unsigned short)(ra.y >> 16));
    float pa = q0 * a0 + q1 * a1 + q2 * a2 + q3 * a3;
    pa += __shfl_xor(pa, 1, 64);
    pa += __shfl_xor(pa, 2, 64);
    pa += __shfl_xor(pa, 4, 64);
    float wa = __expf(__shfl(pa, srcl, 64));
    denom += wa;
    acc0 += wa * a0; acc1 += wa * a1; acc2 += wa * a2; acc3 += wa * a3;
  }
  if (lane >= 32) {
    float inv = 1.f / (denom + 1e-16f);
    float o0 = gelu_tanh(acc0 * inv);
    float o1 = gelu_tanh(acc1 * inv);
    float o2 = gelu_tanh(acc2 * inv);
    float o3 = gelu_tanh(acc3 * inv);
    uint2 pk;
    pk.x = (unsigned)f2bf(o0) | ((unsigned)f2bf(o1) << 16);
    pk.y = (unsigned)f2bf(o2) | ((unsigned)f2bf(o3) << 16);
    *(uint2*)(AGGb + (size_t)dnode * Cc + (lane - 32) * 4) = pk;
  }
}

// ---------------- launch ----------------
extern "C" void kernel_launch(void* const* d_in, const int* in_sizes, int n_in,
                              void* d_out, int out_size, void* d_ws, size_t ws_size,
                              hipStream_t stream) {
  const float* user_emb = (const float*)d_in[0];
  const float* movie_emb = (const float*)d_in[1];
  const float* phi = (const float*)d_in[2];
  const float* meta_w = (const float*)d_in[3];
  const float* meta_b = (const float*)d_in[4];
  const float* kw = (const float*)d_in[5];
  const float* kb = (const float*)d_in[6];
  const float* qw = (const float*)d_in[7];
  const float* qb = (const float*)d_in[8];
  const float* vw = (const float*)d_in[9];
  const float* vb = (const float*)d_in[10];
  const float* a_rel = (const float*)d_in[11];
  const float* m_rel = (const float*)d_in[12];
  const float* p_rel = (const float*)d_in[13];
  const float* ow = (const float*)d_in[14];
  const float* ob = (const float*)d_in[15];
  const float* skip = (const float*)d_in[16];
  const int* eidx = (const int*)d_in[17];

  int NU = in_sizes[0] / Cc;
  int NM = in_sizes[1] / Cc;
  int E_ = in_sizes[17] / 2;
  int NT = NU + NM;
  const int* esrc = eidx;
  const int* edst = eidx + E_;

  char* ws = (char*)d_ws;
  size_t off = 0;
  auto alloc = [&](size_t bytes) -> char* {
    char* p = ws + off;
    off = (off + bytes + 255) & ~(size_t)255;
    return p;
  };
  unsigned short* Qb = (unsigned short*)alloc((size_t)NT * Cc * 2);
  unsigned short* KVb = (unsigned short*)alloc((size_t)NT * 256 * 2);
  unsigned short* Xb = (unsigned short*)alloc((size_t)NT * Cc * 2);
  unsigned short* AGGb = (unsigned short*)alloc((size_t)NT * Cc * 2);
  unsigned short* WT = (unsigned short*)alloc((size_t)Ll * Tt * 384 * Cc * 2);
  unsigned short* OWT = (unsigned short*)alloc((size_t)Ll * Tt * Cc * Cc * 2);
  float* bQKV = (float*)alloc((size_t)Ll * Tt * 384 * 4);
  float* bO = (float*)alloc((size_t)Ll * Tt * Cc * 4);
  int* rpm = (int*)alloc((size_t)(NM + 1) * 4);
  int* rpu = (int*)alloc((size_t)(NU + 1) * 4);
  int* srcm = (int*)alloc((size_t)E_ * 4);
  int* srcu = (int*)alloc((size_t)E_ * 4);
  int* cntm = (int*)alloc((size_t)NM * 4);
  int* cntu = (int*)alloc((size_t)NU * 4);
  float* xout = (float*)d_out;

  // CSR build
  hipMemsetAsync(cntm, 0, (size_t)NM * 4, stream);
  hipMemsetAsync(cntu, 0, (size_t)NU * 4, stream);
  hist_kernel<<<(E_ + 255) / 256, 256, 0, stream>>>(esrc, edst, E_, cntu, cntm);
  scan_kernel<<<1, 1024, 0, stream>>>(cntm, rpm, NM);
  scan_kernel<<<1, 1024, 0, stream>>>(cntu, rpu, NU);
  hipMemsetAsync(cntm, 0, (size_t)NM * 4, stream);
  hipMemsetAsync(cntu, 0, (size_t)NU * 4, stream);
  scatter_kernel<<<(E_ + 255) / 256, 256, 0, stream>>>(esrc, edst, E_, rpm, rpu,
                                                       cntm, cntu, srcm, srcu, NU);

  prep_weights<<<dim3(512, 4), 128, 0, stream>>>(kw, kb, qw, qb, vw, vb, a_rel, m_rel,
                                                 p_rel, ow, ob, WT, bQKV, OWT, bO);
  init_kernel<<<(NT * Cc + 255) / 256, 256, 0, stream>>>(user_emb, movie_emb, phi,
                                                         meta_w, meta_b, xout, Xb, NU, NM);

  for (int l = 0; l < Ll; ++l) {
    for (int t = 0; t < Tt; ++t) {
      int n = t ? NM : NU;
      int node0 = t ? NU : 0;
      int lt = l * Tt + t;
      mfma_gemm<6, 0><<<(n + 255) / 256, 256, 0, stream>>>(
          n, (const bf16*)(Xb + (size_t)node0 * Cc), (const bf16*)(WT + (size_t)lt * 384 * Cc),
          bQKV + (size_t)lt * 384, Qb + (size_t)node0 * Cc, KVb + (size_t)node0 * 256,
          nullptr, nullptr, nullptr);
    }
    agg_kernel<<<(NT + 3) / 4, 256, 0, stream>>>(rpm, srcm, rpu, srcu, Qb, KVb, AGGb, NM, NU);
    for (int t = 0; t < Tt; ++t) {
      int n = t ? NM : NU;
      int node0 = t ? NU : 0;
      int lt = l * Tt + t;
      mfma_gemm<2, 1><<<(n + 255) / 256, 256, 0, stream>>>(
          n, (const bf16*)(AGGb + (size_t)node0 * Cc), (const bf16*)(OWT + (size_t)lt * Cc * Cc),
          bO + (size_t)lt * Cc, nullptr, nullptr, xout + (size_t)node0 * Cc,
          Xb + (size_t)node0 * Cc, skip + lt);
    }
  }
}

// Round 3
// 450.049 us; speedup vs baseline: 2.2347x; 1.7369x over previous
//
#include <hip/hip_runtime.h>
#include <hip/hip_bf16.h>

#define Cc 128
#define Hh 4
#define Dd 32
#define DPHI2 64
#define Ll 2
#define Tt 2
#define Rr 2

typedef __hip_bfloat16 bf16;
using short8 = __attribute__((ext_vector_type(8))) short;
using f32x4 = __attribute__((ext_vector_type(4))) float;

__device__ __forceinline__ unsigned short f2bf(float f) {
  union { float f; unsigned u; } v; v.f = f;
  unsigned r = v.u + 0x7fff + ((v.u >> 16) & 1);
  return (unsigned short)(r >> 16);
}
__device__ __forceinline__ float bf2f(unsigned short b) {
  union { unsigned u; float f; } v; v.u = ((unsigned)b) << 16;
  return v.f;
}
__device__ __forceinline__ float bflo(unsigned u) {
  union { unsigned u; float f; } v; v.u = u << 16;
  return v.f;
}
__device__ __forceinline__ float bfhi(unsigned u) {
  union { unsigned u; float f; } v; v.u = u & 0xffff0000u;
  return v.f;
}
__device__ __forceinline__ float gelu_tanh(float x) {
  float u = 0.7978845608028654f * (x + 0.044715f * x * x * x);
  float t = 1.f - 2.f / (__expf(2.f * u) + 1.f);  // tanh(u)
  return 0.5f * x * (1.f + t);
}

// ---------------- CSR build (contiguous: movies [0,NM) then users [NM,NM+NU)) ----
__global__ void hist_kernel(const int* __restrict__ src, const int* __restrict__ dst,
                            int E_, int NM_, int* cnt) {
  int e = blockIdx.x * 256 + threadIdx.x;
  if (e < E_) {
    atomicAdd(&cnt[dst[e]], 1);
    atomicAdd(&cnt[NM_ + src[e]], 1);
  }
}

__global__ __launch_bounds__(1024) void scan_kernel(const int* __restrict__ cnt,
                                                    int* __restrict__ rowptr, int n) {
  __shared__ int sdata[1024];
  __shared__ int carry_s;
  if (threadIdx.x == 0) { carry_s = 0; rowptr[0] = 0; }
  __syncthreads();
  for (int base = 0; base < n; base += 4096) {
    int i0 = base + (int)threadIdx.x * 4;
    int a0 = (i0 + 0 < n) ? cnt[i0 + 0] : 0;
    int a1 = (i0 + 1 < n) ? cnt[i0 + 1] : 0;
    int a2 = (i0 + 2 < n) ? cnt[i0 + 2] : 0;
    int a3 = (i0 + 3 < n) ? cnt[i0 + 3] : 0;
    int s = a0 + a1 + a2 + a3;
    sdata[threadIdx.x] = s;
    __syncthreads();
    for (int off = 1; off < 1024; off <<= 1) {
      int t = (threadIdx.x >= (unsigned)off) ? sdata[threadIdx.x - off] : 0;
      __syncthreads();
      sdata[threadIdx.x] += t;
      __syncthreads();
    }
    int incl = sdata[threadIdx.x];
    int run = carry_s + incl - s;
    if (i0 + 0 < n) rowptr[i0 + 1] = run + a0;
    if (i0 + 1 < n) rowptr[i0 + 2] = run + a0 + a1;
    if (i0 + 2 < n) rowptr[i0 + 3] = run + a0 + a1 + a2;
    if (i0 + 3 < n) rowptr[i0 + 4] = run + s;
    __syncthreads();
    if (threadIdx.x == 1023) carry_s = carry_s + incl;
    __syncthreads();
  }
}

__global__ void scatter_kernel(const int* __restrict__ src, const int* __restrict__ dst, int E_,
                               const int* __restrict__ rowptr, int* cnt,
                               int* __restrict__ srcAll, int NU_, int NM_) {
  int e = blockIdx.x * 256 + threadIdx.x;
  if (e < E_) {
    int s = src[e], d = dst[e];
    int pm = rowptr[d] + atomicAdd(&cnt[d], 1);
    srcAll[pm] = s;                 // user global row
    int pu = rowptr[NM_ + s] + atomicAdd(&cnt[NM_ + s], 1);
    srcAll[pu] = NU_ + d;           // movie global row
  }
}

// ---------------- weight prep ----------------
// WT[lt][384][128] bf16 (pre-transposed fused [WQ | kw@a_rel*scale | vw@m_rel]),
// bQKV[lt][384] f32, OWT[lt][128][128] bf16 (ow^T), bO[lt][128] f32.
__global__ __launch_bounds__(128) void prep_weights(
    const float* __restrict__ kw, const float* __restrict__ kb,
    const float* __restrict__ qw, const float* __restrict__ qb,
    const float* __restrict__ vw, const float* __restrict__ vb,
    const float* __restrict__ a_rel, const float* __restrict__ m_rel,
    const float* __restrict__ p_rel, const float* __restrict__ ow,
    const float* __restrict__ ob,
    unsigned short* __restrict__ WT, float* __restrict__ bQKV,
    unsigned short* __restrict__ OWT, float* __restrict__ bO) {
  int g = blockIdx.x;   // 0..511
  int lt = blockIdx.y;  // 0..3
  int l = lt >> 1, t = lt & 1, r = t;
  int k = threadIdx.x;
  const float inv_sqrt_d = 0.17677669529663687f;
  float val, bval;
  if (g < 128) {
    val = qw[((size_t)lt * Cc + k) * Cc + g];
    bval = qb[(size_t)lt * Cc + g];
  } else if (g < 384) {
    int isV = (g >= 256);
    int n = g - (isV ? 256 : 128);
    int h = n >> 5, e = n & 31;
    const float* W = (isV ? vw : kw) + (size_t)lt * Cc * Cc;
    const float* bb = (isV ? vb : kb) + (size_t)lt * Cc;
    const float* Ah = (isV ? m_rel : a_rel) + (((size_t)l * Rr + r) * Hh + h) * Dd * Dd;
    float s = 0.f, sb = 0.f;
    for (int d = 0; d < Dd; ++d) {
      float ae = Ah[d * Dd + e];
      s += W[(size_t)k * Cc + h * Dd + d] * ae;
      sb += bb[h * Dd + d] * ae;
    }
    float scale = isV ? 1.f : p_rel[((size_t)l * Rr + r) * Hh + h] * inv_sqrt_d;
    val = s * scale;
    bval = sb * scale;
  } else {
    int n = g - 384;
    val = ow[((size_t)lt * Cc + k) * Cc + n];
    bval = ob[(size_t)lt * Cc + n];
  }
  if (g < 384) {
    WT[((size_t)lt * 384 + g) * Cc + k] = f2bf(val);
    if (k == 0) bQKV[(size_t)lt * 384 + g] = bval;
  } else {
    OWT[((size_t)lt * Cc + (g - 384)) * Cc + k] = f2bf(val);
    if (k == 0) bO[(size_t)lt * Cc + (g - 384)] = bval;
  }
}

// ---------------- init: xout (f32) + Xb (bf16) ----------------
__global__ void init_kernel(const float* __restrict__ ue, const float* __restrict__ me,
                            const float* __restrict__ phi, const float* __restrict__ mw,
                            const float* __restrict__ mb,
                            float* __restrict__ xout, unsigned short* __restrict__ Xb,
                            int NU_, int NM_) {
  int i = blockIdx.x * 256 + threadIdx.x;
  int totalU = NU_ * Cc;
  if (i < totalU) {
    float v = ue[i];
    xout[i] = v;
    Xb[i] = f2bf(v);
  } else {
    int j = i - totalU;
    if (j >= NM_ * Cc) return;
    int m = j >> 7, c = j & 127;
    float s = me[j] + mb[c];
    const float* ph = phi + (size_t)m * DPHI2;
    for (int d = 0; d < DPHI2; ++d) s += ph[d] * mw[d * Cc + c];
    xout[i] = s;
    Xb[i] = f2bf(s);
  }
}

// ---------------- register-only MFMA GEMM, swapped operands (C^T layout) --------
// Covers BOTH node types in one launch: blocks [0,NBU) = users, rest = movies.
// 32 rows/wave, 128 rows/block. Lane holds 1 row x 4 consecutive cols per acc reg.
// MODE 0: fused QKV proj -> Qb (cols 0-127), KVb (cols 128-383, row stride 256)
// MODE 1: out proj + skip-mix -> xout (f32) + Xb (bf16)
template <int NCH, int MODE>
__global__ __launch_bounds__(256, 2) void mfma_gemm(
    int NBU_, int NU_, int NM_,
    const bf16* __restrict__ Abase,
    const bf16* __restrict__ WTl, const float* __restrict__ biasl,
    unsigned short* __restrict__ Qb, unsigned short* __restrict__ KVb,
    float* __restrict__ xout, unsigned short* __restrict__ Xb,
    const float* __restrict__ skipl) {
  int bx = blockIdx.x;
  int t, row0, M, base;
  if (bx < NBU_) { t = 0; row0 = bx * 128; M = NU_; base = 0; }
  else { t = 1; row0 = (bx - NBU_) * 128; M = NM_; base = NU_; }
  const bf16* BT = WTl + (size_t)t * (NCH * 64) * Cc;
  const float* bias = biasl + (size_t)t * (NCH * 64);
  int wid = threadIdx.x >> 6, lane = threadIdx.x & 63;
  int rw = row0 + wid * 32;
  if (rw >= M) return;
  int lr = lane & 15, lk8 = (lane >> 4) * 8;
  short8 a[2][4];
#pragma unroll
  for (int mt = 0; mt < 2; ++mt) {
    int r = rw + mt * 16 + lr;
    const bf16* ap = Abase + (size_t)(base + r) * Cc + lk8;
#pragma unroll
    for (int kk = 0; kk < 4; ++kk) {
      short8 v = {};
      if (r < M) v = *(const short8*)(ap + kk * 32);
      a[mt][kk] = v;
    }
  }
  float g = 0.f;
  if (MODE == 1) g = 1.f / (1.f + __expf(-skipl[t]));
#pragma unroll
  for (int ch = 0; ch < NCH; ++ch) {
    short8 b[4][4];
#pragma unroll
    for (int nt = 0; nt < 4; ++nt) {
      const bf16* bp = BT + (size_t)(ch * 64 + nt * 16 + lr) * Cc + lk8;
#pragma unroll
      for (int kk = 0; kk < 4; ++kk) b[nt][kk] = *(const short8*)(bp + kk * 32);
    }
    f32x4 acc[2][4];
#pragma unroll
    for (int mt = 0; mt < 2; ++mt)
#pragma unroll
      for (int nt = 0; nt < 4; ++nt) acc[mt][nt] = (f32x4){0.f, 0.f, 0.f, 0.f};
#pragma unroll
    for (int kk = 0; kk < 4; ++kk)
#pragma unroll
      for (int mt = 0; mt < 2; ++mt)
#pragma unroll
        for (int nt = 0; nt < 4; ++nt)
          acc[mt][nt] = __builtin_amdgcn_mfma_f32_16x16x32_bf16(
              b[nt][kk], a[mt][kk], acc[mt][nt], 0, 0, 0);  // C^T: lane = 1 row, 4 cols
#pragma unroll
    for (int mt = 0; mt < 2; ++mt) {
      int r = rw + mt * 16 + lr;
      if (r >= M) continue;
      size_t grow = (size_t)(base + r);
#pragma unroll
      for (int nt = 0; nt < 4; ++nt) {
        int cb = ch * 64 + nt * 16 + 4 * (lane >> 4);
        float4 b4 = *(const float4*)&bias[cb];
        float v0 = acc[mt][nt][0] + b4.x;
        float v1 = acc[mt][nt][1] + b4.y;
        float v2 = acc[mt][nt][2] + b4.z;
        float v3 = acc[mt][nt][3] + b4.w;
        if (MODE == 0) {
          uint2 pk;
          pk.x = (unsigned)f2bf(v0) | ((unsigned)f2bf(v1) << 16);
          pk.y = (unsigned)f2bf(v2) | ((unsigned)f2bf(v3) << 16);
          if (cb < Cc)
            *(uint2*)(Qb + grow * Cc + cb) = pk;
          else
            *(uint2*)(KVb + grow * 256 + (cb - Cc)) = pk;
        } else {
          float* xp = xout + grow * Cc + cb;
          float4 old = *(const float4*)xp;
          float n0 = g * v0 + (1.f - g) * old.x;
          float n1 = g * v1 + (1.f - g) * old.y;
          float n2 = g * v2 + (1.f - g) * old.z;
          float n3 = g * v3 + (1.f - g) * old.w;
          *(float4*)xp = make_float4(n0, n1, n2, n3);
          uint2 pk;
          pk.x = (unsigned)f2bf(n0) | ((unsigned)f2bf(n1) << 16);
          pk.y = (unsigned)f2bf(n2) | ((unsigned)f2bf(n3) << 16);
          *(uint2*)(Xb + grow * Cc + cb) = pk;
        }
      }
    }
  }
}

// ---------------- fused softmax+agg: 1 wave per dst, half-wave per edge ---------
// KV rows: [KE(128) | VE(128)] bf16 (512B). Half h = lane>>5 owns edge e+h of a
// pair; its 32 lanes each handle 4 channels (uint2). xor-butterfly 1,2,4 gives
// every lane its head's full logit (no broadcast needed). Halves combined at end
// via shfl_xor 32. gelu fused into epilogue.
__global__ __launch_bounds__(256) void agg_kernel(
    const int* __restrict__ rowptr, const int* __restrict__ srcAll,
    const unsigned short* __restrict__ Qb, const unsigned short* __restrict__ KVb,
    unsigned short* __restrict__ AGGb, int NM_, int NU_) {
  int wid = threadIdx.x >> 6, lane = threadIdx.x & 63;
  int W = blockIdx.x * 4 + wid;
  int dnode, beg, end;
  if (W < NM_) {
    dnode = NU_ + W; beg = rowptr[W]; end = rowptr[W + 1];
  } else {
    int u = W - NM_;
    if (u >= NU_) return;
    dnode = u; beg = rowptr[NM_ + u]; end = rowptr[NM_ + u + 1];
  }
  int half = lane >> 5, l31 = lane & 31;
  uint2 qv = *(const uint2*)(Qb + (size_t)dnode * Cc + l31 * 4);
  float q0 = bflo(qv.x), q1 = bfhi(qv.x), q2 = bflo(qv.y), q3 = bfhi(qv.y);
  float acc0 = 0.f, acc1 = 0.f, acc2 = 0.f, acc3 = 0.f, denom = 0.f;

#define PAIR(E, MASKED)                                                          \
  {                                                                              \
    int ei = (E) + half;                                                         \
    int ec = MASKED ? min(ei, end - 1) : ei;                                     \
    int s = srcAll[ec];                                                          \
    const unsigned short* kvrow = KVb + (size_t)s * 256;                         \
    uint2 ke = *(const uint2*)(kvrow + l31 * 4);                                 \
    uint2 ve = *(const uint2*)(kvrow + 128 + l31 * 4);                           \
    float p = q0 * bflo(ke.x) + q1 * bfhi(ke.x) + q2 * bflo(ke.y) + q3 * bfhi(ke.y); \
    p += __shfl_xor(p, 1, 64);                                                   \
    p += __shfl_xor(p, 2, 64);                                                   \
    p += __shfl_xor(p, 4, 64);                                                   \
    float w = __expf(p);                                                         \
    if (MASKED) w = (ei < end) ? w : 0.f;                                        \
    denom += w;                                                                  \
    acc0 += w * bflo(ve.x); acc1 += w * bfhi(ve.x);                              \
    acc2 += w * bflo(ve.y); acc3 += w * bfhi(ve.y);                              \
  }

  int e = beg;
  for (; e + 4 <= end; e += 4) { PAIR(e, 0) PAIR(e + 2, 0) }
  for (; e < end; e += 2) PAIR(e, 1)
#undef PAIR

  denom += __shfl_xor(denom, 32, 64);
  acc0 += __shfl_xor(acc0, 32, 64);
  acc1 += __shfl_xor(acc1, 32, 64);
  acc2 += __shfl_xor(acc2, 32, 64);
  acc3 += __shfl_xor(acc3, 32, 64);
  if (lane < 32) {
    float inv = 1.f / (denom + 1e-16f);
    float o0 = gelu_tanh(acc0 * inv);
    float o1 = gelu_tanh(acc1 * inv);
    float o2 = gelu_tanh(acc2 * inv);
    float o3 = gelu_tanh(acc3 * inv);
    uint2 pk;
    pk.x = (unsigned)f2bf(o0) | ((unsigned)f2bf(o1) << 16);
    pk.y = (unsigned)f2bf(o2) | ((unsigned)f2bf(o3) << 16);
    *(uint2*)(AGGb + (size_t)dnode * Cc + l31 * 4) = pk;
  }
}

// ---------------- launch ----------------
extern "C" void kernel_launch(void* const* d_in, const int* in_sizes, int n_in,
                              void* d_out, int out_size, void* d_ws, size_t ws_size,
                              hipStream_t stream) {
  const float* user_emb = (const float*)d_in[0];
  const float* movie_emb = (const float*)d_in[1];
  const float* phi = (const float*)d_in[2];
  const float* meta_w = (const float*)d_in[3];
  const float* meta_b = (const float*)d_in[4];
  const float* kw = (const float*)d_in[5];
  const float* kb = (const float*)d_in[6];
  const float* qw = (const float*)d_in[7];
  const float* qb = (const float*)d_in[8];
  const float* vw = (const float*)d_in[9];
  const float* vb = (const float*)d_in[10];
  const float* a_rel = (const float*)d_in[11];
  const float* m_rel = (const float*)d_in[12];
  const float* p_rel = (const float*)d_in[13];
  const float* ow = (const float*)d_in[14];
  const float* ob = (const float*)d_in[15];
  const float* skip = (const float*)d_in[16];
  const int* eidx = (const int*)d_in[17];

  int NU = in_sizes[0] / Cc;
  int NM = in_sizes[1] / Cc;
  int E_ = in_sizes[17] / 2;
  int NT = NU + NM;
  const int* esrc = eidx;
  const int* edst = eidx + E_;

  char* ws = (char*)d_ws;
  size_t off = 0;
  auto alloc = [&](size_t bytes) -> char* {
    char* p = ws + off;
    off = (off + bytes + 255) & ~(size_t)255;
    return p;
  };
  unsigned short* Qb = (unsigned short*)alloc((size_t)NT * Cc * 2);
  unsigned short* KVb = (unsigned short*)alloc((size_t)NT * 256 * 2);
  unsigned short* Xb = (unsigned short*)alloc((size_t)NT * Cc * 2);
  unsigned short* AGGb = (unsigned short*)alloc((size_t)NT * Cc * 2);
  unsigned short* WT = (unsigned short*)alloc((size_t)Ll * Tt * 384 * Cc * 2);
  unsigned short* OWT = (unsigned short*)alloc((size_t)Ll * Tt * Cc * Cc * 2);
  float* bQKV = (float*)alloc((size_t)Ll * Tt * 384 * 4);
  float* bO = (float*)alloc((size_t)Ll * Tt * Cc * 4);
  int* rowptr = (int*)alloc((size_t)(NT + 1) * 4);
  int* srcAll = (int*)alloc((size_t)2 * E_ * 4);
  int* cnt = (int*)alloc((size_t)NT * 4);
  float* xout = (float*)d_out;

  // CSR build (movies [0,NM), users [NM,NT) -> one scan, one srcAll)
  hipMemsetAsync(cnt, 0, (size_t)NT * 4, stream);
  hist_kernel<<<(E_ + 255) / 256, 256, 0, stream>>>(esrc, edst, E_, NM, cnt);
  scan_kernel<<<1, 1024, 0, stream>>>(cnt, rowptr, NT);
  hipMemsetAsync(cnt, 0, (size_t)NT * 4, stream);
  scatter_kernel<<<(E_ + 255) / 256, 256, 0, stream>>>(esrc, edst, E_, rowptr, cnt,
                                                       srcAll, NU, NM);

  prep_weights<<<dim3(512, 4), 128, 0, stream>>>(kw, kb, qw, qb, vw, vb, a_rel, m_rel,
                                                 p_rel, ow, ob, WT, bQKV, OWT, bO);
  init_kernel<<<(NT * Cc + 255) / 256, 256, 0, stream>>>(user_emb, movie_emb, phi,
                                                         meta_w, meta_b, xout, Xb, NU, NM);

  int NBU = (NU + 127) / 128;
  int NBM = (NM + 127) / 128;
  dim3 ggrid(NBU + NBM);
  for (int l = 0; l < Ll; ++l) {
    mfma_gemm<6, 0><<<ggrid, 256, 0, stream>>>(
        NBU, NU, NM, (const bf16*)Xb, (const bf16*)(WT + (size_t)l * 2 * 384 * Cc),
        bQKV + (size_t)l * 2 * 384, Qb, KVb, nullptr, nullptr, nullptr);
    agg_kernel<<<(NT + 3) / 4, 256, 0, stream>>>(rowptr, srcAll, Qb, KVb, AGGb, NM, NU);
    mfma_gemm<2, 1><<<ggrid, 256, 0, stream>>>(
        NBU, NU, NM, (const bf16*)AGGb, (const bf16*)(OWT + (size_t)l * 2 * Cc * Cc),
        bO + (size_t)l * 2 * Cc, nullptr, nullptr, xout, Xb, skip + (size_t)l * 2);
  }
}

// Round 5
// 404.815 us; speedup vs baseline: 2.4844x; 1.1117x over previous
//
#include <hip/hip_runtime.h>
#include <hip/hip_bf16.h>

#define Cc 128
#define Hh 4
#define Dd 32
#define DPHI2 64
#define Ll 2
#define Tt 2
#define Rr 2

typedef __hip_bfloat16 bf16;
using short8 = __attribute__((ext_vector_type(8))) short;
using f32x4 = __attribute__((ext_vector_type(4))) float;
typedef _Float16 h2 __attribute__((ext_vector_type(2)));
typedef __fp16 fp16x2 __attribute__((ext_vector_type(2)));

__device__ __forceinline__ unsigned short f2bf(float f) {
  union { float f; unsigned u; } v; v.f = f;
  unsigned r = v.u + 0x7fff + ((v.u >> 16) & 1);
  return (unsigned short)(r >> 16);
}
__device__ __forceinline__ float bflo(unsigned u) {
  union { unsigned u; float f; } v; v.u = u << 16;
  return v.f;
}
__device__ __forceinline__ float bfhi(unsigned u) {
  union { unsigned u; float f; } v; v.u = u & 0xffff0000u;
  return v.f;
}
__device__ __forceinline__ h2 u2h(unsigned u) {
  union { unsigned u; h2 h; } v; v.u = u; return v.h;
}
__device__ __forceinline__ unsigned pkh(float a, float b) {
  union { unsigned u; fp16x2 h; } v;
  v.h = __builtin_amdgcn_cvt_pkrtz(a, b);
  return v.u;
}
__device__ __forceinline__ float dot2h(unsigned a, unsigned b, float c) {
#if __has_builtin(__builtin_amdgcn_fdot2)
  return __builtin_amdgcn_fdot2(u2h(a), u2h(b), c, false);
#else
  h2 ha = u2h(a), hb = u2h(b);
  return c + (float)ha[0] * (float)hb[0] + (float)ha[1] * (float)hb[1];
#endif
}
__device__ __forceinline__ float gelu_tanh(float x) {
  float u = 0.7978845608028654f * (x + 0.044715f * x * x * x);
  float t = 1.f - 2.f / (__expf(2.f * u) + 1.f);  // tanh(u)
  return 0.5f * x * (1.f + t);
}

// ---------------- CSR build (contiguous: movies [0,NM) then users [NM,NM+NU)) ----
__global__ void hist_kernel(const int* __restrict__ src, const int* __restrict__ dst,
                            int E_, int NM_, int* cnt) {
  int e = blockIdx.x * 256 + threadIdx.x;
  if (e < E_) {
    atomicAdd(&cnt[dst[e]], 1);
    atomicAdd(&cnt[NM_ + src[e]], 1);
  }
}

// 3-phase parallel scan: 1024 elems per block
__global__ __launch_bounds__(256) void scan_p1(const int* __restrict__ cnt, int n,
                                               int* __restrict__ psum) {
  int i0 = blockIdx.x * 1024 + threadIdx.x * 4;
  int s = 0;
#pragma unroll
  for (int j = 0; j < 4; ++j) {
    int i = i0 + j;
    if (i < n) s += cnt[i];
  }
#pragma unroll
  for (int off = 1; off < 64; off <<= 1) s += __shfl_xor(s, off, 64);
  __shared__ int wsum[4];
  if ((threadIdx.x & 63) == 0) wsum[threadIdx.x >> 6] = s;
  __syncthreads();
  if (threadIdx.x == 0) psum[blockIdx.x] = wsum[0] + wsum[1] + wsum[2] + wsum[3];
}
__global__ void scan_p2(int* psum, int nb) {
  if (threadIdx.x == 0 && blockIdx.x == 0) {
    int run = 0;
    for (int i = 0; i < nb; ++i) { int v = psum[i]; psum[i] = run; run += v; }
  }
}
__global__ __launch_bounds__(256) void scan_p3(const int* __restrict__ cnt, int n,
                                               const int* __restrict__ psum,
                                               int* __restrict__ rowptr) {
  __shared__ int sdata[256];
  int i0 = blockIdx.x * 1024 + threadIdx.x * 4;
  int a0 = (i0 + 0 < n) ? cnt[i0 + 0] : 0;
  int a1 = (i0 + 1 < n) ? cnt[i0 + 1] : 0;
  int a2 = (i0 + 2 < n) ? cnt[i0 + 2] : 0;
  int a3 = (i0 + 3 < n) ? cnt[i0 + 3] : 0;
  int s = a0 + a1 + a2 + a3;
  sdata[threadIdx.x] = s;
  __syncthreads();
  for (int off = 1; off < 256; off <<= 1) {
    int t = ((int)threadIdx.x >= off) ? sdata[threadIdx.x - off] : 0;
    __syncthreads();
    sdata[threadIdx.x] += t;
    __syncthreads();
  }
  int run = psum[blockIdx.x] + sdata[threadIdx.x] - s;
  if (i0 + 0 < n) rowptr[i0 + 1] = run + a0;
  if (i0 + 1 < n) rowptr[i0 + 2] = run + a0 + a1;
  if (i0 + 2 < n) rowptr[i0 + 3] = run + a0 + a1 + a2;
  if (i0 + 3 < n) rowptr[i0 + 4] = run + s;
  if (blockIdx.x == 0 && threadIdx.x == 0) rowptr[0] = 0;
}

// srcAll holds BYTE offsets into KVc (global_row * 512)
__global__ void scatter_kernel(const int* __restrict__ src, const int* __restrict__ dst, int E_,
                               const int* __restrict__ rowptr, int* cnt,
                               int* __restrict__ srcAll, int NU_, int NM_) {
  int e = blockIdx.x * 256 + threadIdx.x;
  if (e < E_) {
    int s = src[e], d = dst[e];
    int pm = rowptr[d] + atomicAdd(&cnt[d], 1);
    srcAll[pm] = s << 9;                    // user global row * 512
    int pu = rowptr[NM_ + s] + atomicAdd(&cnt[NM_ + s], 1);
    srcAll[pu] = (NU_ + d) << 9;            // movie global row * 512
  }
}

// ---------------- weight prep ----------------
// WT[lt][384][128] bf16: fused [qw*log2e | kw@a_rel*p/sqrtD | vw@m_rel] pre-transposed.
__global__ __launch_bounds__(128) void prep_weights(
    const float* __restrict__ kw, const float* __restrict__ kb,
    const float* __restrict__ qw, const float* __restrict__ qb,
    const float* __restrict__ vw, const float* __restrict__ vb,
    const float* __restrict__ a_rel, const float* __restrict__ m_rel,
    const float* __restrict__ p_rel, const float* __restrict__ ow,
    const float* __restrict__ ob,
    unsigned short* __restrict__ WT, float* __restrict__ bQKV,
    unsigned short* __restrict__ OWT, float* __restrict__ bO) {
  int g = blockIdx.x;   // 0..511
  int lt = blockIdx.y;  // 0..3
  int l = lt >> 1, t = lt & 1, r = t;
  int k = threadIdx.x;
  const float inv_sqrt_d = 0.17677669529663687f;
  const float LOG2E = 1.4426950408889634f;
  float val, bval;
  if (g < 128) {
    val = qw[((size_t)lt * Cc + k) * Cc + g] * LOG2E;
    bval = qb[(size_t)lt * Cc + g] * LOG2E;
  } else if (g < 384) {
    int isV = (g >= 256);
    int n = g - (isV ? 256 : 128);
    int h = n >> 5, e = n & 31;
    const float* W = (isV ? vw : kw) + (size_t)lt * Cc * Cc;
    const float* bb = (isV ? vb : kb) + (size_t)lt * Cc;
    const float* Ah = (isV ? m_rel : a_rel) + (((size_t)l * Rr + r) * Hh + h) * Dd * Dd;
    float s = 0.f, sb = 0.f;
    for (int d = 0; d < Dd; ++d) {
      float ae = Ah[d * Dd + e];
      s += W[(size_t)k * Cc + h * Dd + d] * ae;
      sb += bb[h * Dd + d] * ae;
    }
    float scale = isV ? 1.f : p_rel[((size_t)l * Rr + r) * Hh + h] * inv_sqrt_d;
    val = s * scale;
    bval = sb * scale;
  } else {
    int n = g - 384;
    val = ow[((size_t)lt * Cc + k) * Cc + n];
    bval = ob[(size_t)lt * Cc + n];
  }
  if (g < 384) {
    WT[((size_t)lt * 384 + g) * Cc + k] = f2bf(val);
    if (k == 0) bQKV[(size_t)lt * 384 + g] = bval;
  } else {
    OWT[((size_t)lt * Cc + (g - 384)) * Cc + k] = f2bf(val);
    if (k == 0) bO[(size_t)lt * Cc + (g - 384)] = bval;
  }
}

// ---------------- init: xout (f32) + Xb (bf16) ----------------
__global__ void init_kernel(const float* __restrict__ ue, const float* __restrict__ me,
                            const float* __restrict__ phi, const float* __restrict__ mw,
                            const float* __restrict__ mb,
                            float* __restrict__ xout, unsigned short* __restrict__ Xb,
                            int NU_, int NM_) {
  int i = blockIdx.x * 256 + threadIdx.x;
  int totalU = NU_ * Cc;
  if (i < totalU) {
    float v = ue[i];
    xout[i] = v;
    Xb[i] = f2bf(v);
  } else {
    int j = i - totalU;
    if (j >= NM_ * Cc) return;
    int m = j >> 7, c = j & 127;
    float s = me[j] + mb[c];
    const float* ph = phi + (size_t)m * DPHI2;
    for (int d = 0; d < DPHI2; ++d) s += ph[d] * mw[d * Cc + c];
    xout[i] = s;
    Xb[i] = f2bf(s);
  }
}

// ---------------- register-only MFMA GEMM, swapped operands (C^T layout) --------
// blocks [0,NBU) = users, rest = movies. 32 rows/wave, 128 rows/block.
// MODE 0: QKV proj. Q cols [0,128) -> Qc (f16, 256B rows); KE cols [128,256) ->
//   KV chunk first 8B (f16); VE cols [256,384) -> KV chunk second 8B (bf16).
//   KV row = 32 chunks x 16B = 512B; chunk c serves channels 4c..4c+3.
// MODE 1: out proj + skip-mix -> xout (f32) + Xb (bf16)
template <int NCH, int MODE>
__global__ __launch_bounds__(256, 2) void mfma_gemm(
    int NBU_, int NU_, int NM_,
    const bf16* __restrict__ Abase,
    const bf16* __restrict__ WTl, const float* __restrict__ biasl,
    char* __restrict__ Qc, char* __restrict__ KVc,
    float* __restrict__ xout, unsigned short* __restrict__ Xb,
    const float* __restrict__ skipl) {
  int bx = blockIdx.x;
  int t, row0, M, base;
  if (bx < NBU_) { t = 0; row0 = bx * 128; M = NU_; base = 0; }
  else { t = 1; row0 = (bx - NBU_) * 128; M = NM_; base = NU_; }
  const bf16* BT = WTl + (size_t)t * (NCH * 64) * Cc;
  const float* bias = biasl + (size_t)t * (NCH * 64);
  int wid = threadIdx.x >> 6, lane = threadIdx.x & 63;
  int rw = row0 + wid * 32;
  if (rw >= M) return;
  int lr = lane & 15, lk8 = (lane >> 4) * 8;
  short8 a[2][4];
#pragma unroll
  for (int mt = 0; mt < 2; ++mt) {
    int r = rw + mt * 16 + lr;
    const bf16* ap = Abase + (size_t)(base + r) * Cc + lk8;
#pragma unroll
    for (int kk = 0; kk < 4; ++kk) {
      short8 v = {};
      if (r < M) v = *(const short8*)(ap + kk * 32);
      a[mt][kk] = v;
    }
  }
  float g = 0.f;
  if (MODE == 1) g = 1.f / (1.f + __expf(-skipl[t]));
#pragma unroll
  for (int ch = 0; ch < NCH; ++ch) {
    short8 b[4][4];
#pragma unroll
    for (int nt = 0; nt < 4; ++nt) {
      const bf16* bp = BT + (size_t)(ch * 64 + nt * 16 + lr) * Cc + lk8;
#pragma unroll
      for (int kk = 0; kk < 4; ++kk) b[nt][kk] = *(const short8*)(bp + kk * 32);
    }
    f32x4 acc[2][4];
#pragma unroll
    for (int mt = 0; mt < 2; ++mt)
#pragma unroll
      for (int nt = 0; nt < 4; ++nt) acc[mt][nt] = (f32x4){0.f, 0.f, 0.f, 0.f};
#pragma unroll
    for (int kk = 0; kk < 4; ++kk)
#pragma unroll
      for (int mt = 0; mt < 2; ++mt)
#pragma unroll
        for (int nt = 0; nt < 4; ++nt)
          acc[mt][nt] = __builtin_amdgcn_mfma_f32_16x16x32_bf16(
              b[nt][kk], a[mt][kk], acc[mt][nt], 0, 0, 0);  // C^T: lane = 1 row, 4 cols
#pragma unroll
    for (int mt = 0; mt < 2; ++mt) {
      int r = rw + mt * 16 + lr;
      if (r >= M) continue;
      size_t grow = (size_t)(base + r);
#pragma unroll
      for (int nt = 0; nt < 4; ++nt) {
        int cb = ch * 64 + nt * 16 + 4 * (lane >> 4);
        float4 b4 = *(const float4*)&bias[cb];
        float v0 = acc[mt][nt][0] + b4.x;
        float v1 = acc[mt][nt][1] + b4.y;
        float v2 = acc[mt][nt][2] + b4.z;
        float v3 = acc[mt][nt][3] + b4.w;
        if (MODE == 0) {
          if (cb < Cc) {
            uint2 pk;
            pk.x = pkh(v0, v1); pk.y = pkh(v2, v3);
            *(uint2*)(Qc + grow * 256 + cb * 2) = pk;
          } else if (cb < 256) {
            uint2 pk;
            pk.x = pkh(v0, v1); pk.y = pkh(v2, v3);
            *(uint2*)(KVc + grow * 512 + ((cb & 127) >> 2) * 16) = pk;
          } else {
            uint2 pk;
            pk.x = (unsigned)f2bf(v0) | ((unsigned)f2bf(v1) << 16);
            pk.y = (unsigned)f2bf(v2) | ((unsigned)f2bf(v3) << 16);
            *(uint2*)(KVc + grow * 512 + ((cb & 127) >> 2) * 16 + 8) = pk;
          }
        } else {
          float* xp = xout + grow * Cc + cb;
          float4 old = *(const float4*)xp;
          float n0 = g * v0 + (1.f - g) * old.x;
          float n1 = g * v1 + (1.f - g) * old.y;
          float n2 = g * v2 + (1.f - g) * old.z;
          float n3 = g * v3 + (1.f - g) * old.w;
          *(float4*)xp = make_float4(n0, n1, n2, n3);
          uint2 pk;
          pk.x = (unsigned)f2bf(n0) | ((unsigned)f2bf(n1) << 16);
          pk.y = (unsigned)f2bf(n2) | ((unsigned)f2bf(n3) << 16);
          *(uint2*)(Xb + grow * Cc + cb) = pk;
        }
      }
    }
  }
}

// ---------------- fused softmax+agg: 1 wave per dst, half-wave per edge ---------
// Per edge per lane: one dwordx4 [ke f16 x4 | ve bf16 x4]; 2x v_dot2 for the
// head-partial logit; xor-butterfly 1,2,4 over the 8-lane head group; w=exp2(p)
// (log2e folded into Q weights). Halves combined via shfl_xor 32. gelu epilogue.
__global__ __launch_bounds__(256) void agg_kernel(
    const int* __restrict__ rowptr, const int* __restrict__ srcAll,
    const char* __restrict__ Qc, const char* __restrict__ KVc,
    unsigned short* __restrict__ AGGb, int NM_, int NU_) {
  int wid = threadIdx.x >> 6, lane = threadIdx.x & 63;
  int W = blockIdx.x * 4 + wid;
  int dnode, beg, end;
  if (W < NM_) {
    dnode = NU_ + W; beg = rowptr[W]; end = rowptr[W + 1];
  } else {
    int u = W - NM_;
    if (u >= NU_) return;
    dnode = u; beg = rowptr[NM_ + u]; end = rowptr[NM_ + u + 1];
  }
  int half = lane >> 5, l31 = lane & 31;
  uint2 qv = *(const uint2*)(Qc + (size_t)dnode * 256 + l31 * 8);
  float acc0 = 0.f, acc1 = 0.f, acc2 = 0.f, acc3 = 0.f, denom = 0.f;

#define PAIR(E, MASKED)                                                          \
  {                                                                              \
    int ei = (E) + half;                                                         \
    int ec = MASKED ? min(ei, end - 1) : ei;                                     \
    int so = srcAll[ec];                                                         \
    uint4 kv = *(const uint4*)(KVc + (size_t)so + l31 * 16);                     \
    float p = dot2h(kv.y, qv.y, dot2h(kv.x, qv.x, 0.f));                         \
    p += __shfl_xor(p, 1, 64);                                                   \
    p += __shfl_xor(p, 2, 64);                                                   \
    p += __shfl_xor(p, 4, 64);                                                   \
    float w = exp2f(p);                                                          \
    if (MASKED) w = (ei < end) ? w : 0.f;                                        \
    denom += w;                                                                  \
    acc0 += w * bflo(kv.z); acc1 += w * bfhi(kv.z);                              \
    acc2 += w * bflo(kv.w); acc3 += w * bfhi(kv.w);                              \
  }

  int e = beg;
  for (; e + 4 <= end; e += 4) { PAIR(e, 0) PAIR(e + 2, 0) }
  for (; e < end; e += 2) PAIR(e, 1)
#undef PAIR

  denom += __shfl_xor(denom, 32, 64);
  acc0 += __shfl_xor(acc0, 32, 64);
  acc1 += __shfl_xor(acc1, 32, 64);
  acc2 += __shfl_xor(acc2, 32, 64);
  acc3 += __shfl_xor(acc3, 32, 64);
  if (lane < 32) {
    float inv = 1.f / (denom + 1e-16f);
    float o0 = gelu_tanh(acc0 * inv);
    float o1 = gelu_tanh(acc1 * inv);
    float o2 = gelu_tanh(acc2 * inv);
    float o3 = gelu_tanh(acc3 * inv);
    uint2 pk;
    pk.x = (unsigned)f2bf(o0) | ((unsigned)f2bf(o1) << 16);
    pk.y = (unsigned)f2bf(o2) | ((unsigned)f2bf(o3) << 16);
    *(uint2*)(AGGb + (size_t)dnode * Cc + l31 * 4) = pk;
  }
}

// ---------------- launch ----------------
extern "C" void kernel_launch(void* const* d_in, const int* in_sizes, int n_in,
                              void* d_out, int out_size, void* d_ws, size_t ws_size,
                              hipStream_t stream) {
  const float* user_emb = (const float*)d_in[0];
  const float* movie_emb = (const float*)d_in[1];
  const float* phi = (const float*)d_in[2];
  const float* meta_w = (const float*)d_in[3];
  const float* meta_b = (const float*)d_in[4];
  const float* kw = (const float*)d_in[5];
  const float* kb = (const float*)d_in[6];
  const float* qw = (const float*)d_in[7];
  const float* qb = (const float*)d_in[8];
  const float* vw = (const float*)d_in[9];
  const float* vb = (const float*)d_in[10];
  const float* a_rel = (const float*)d_in[11];
  const float* m_rel = (const float*)d_in[12];
  const float* p_rel = (const float*)d_in[13];
  const float* ow = (const float*)d_in[14];
  const float* ob = (const float*)d_in[15];
  const float* skip = (const float*)d_in[16];
  const int* eidx = (const int*)d_in[17];

  int NU = in_sizes[0] / Cc;
  int NM = in_sizes[1] / Cc;
  int E_ = in_sizes[17] / 2;
  int NT = NU + NM;
  const int* esrc = eidx;
  const int* edst = eidx + E_;

  char* ws = (char*)d_ws;
  size_t off = 0;
  auto alloc = [&](size_t bytes) -> char* {
    char* p = ws + off;
    off = (off + bytes + 255) & ~(size_t)255;
    return p;
  };
  char* Qc = alloc((size_t)NT * 256);
  char* KVc = alloc((size_t)NT * 512);
  unsigned short* Xb = (unsigned short*)alloc((size_t)NT * Cc * 2);
  unsigned short* AGGb = (unsigned short*)alloc((size_t)NT * Cc * 2);
  unsigned short* WT = (unsigned short*)alloc((size_t)Ll * Tt * 384 * Cc * 2);
  unsigned short* OWT = (unsigned short*)alloc((size_t)Ll * Tt * Cc * Cc * 2);
  float* bQKV = (float*)alloc((size_t)Ll * Tt * 384 * 4);
  float* bO = (float*)alloc((size_t)Ll * Tt * Cc * 4);
  int* rowptr = (int*)alloc((size_t)(NT + 1) * 4);
  int* srcAll = (int*)alloc((size_t)2 * E_ * 4);
  int* cnt = (int*)alloc((size_t)NT * 4);
  int* psum = (int*)alloc((size_t)256 * 4);
  float* xout = (float*)d_out;

  int nblk = (NT + 1023) / 1024;

  // CSR build (movies [0,NM), users [NM,NT))
  hipMemsetAsync(cnt, 0, (size_t)NT * 4, stream);
  hist_kernel<<<(E_ + 255) / 256, 256, 0, stream>>>(esrc, edst, E_, NM, cnt);
  scan_p1<<<nblk, 256, 0, stream>>>(cnt, NT, psum);
  scan_p2<<<1, 64, 0, stream>>>(psum, nblk);
  scan_p3<<<nblk, 256, 0, stream>>>(cnt, NT, psum, rowptr);
  hipMemsetAsync(cnt, 0, (size_t)NT * 4, stream);
  scatter_kernel<<<(E_ + 255) / 256, 256, 0, stream>>>(esrc, edst, E_, rowptr, cnt,
                                                       srcAll, NU, NM);

  prep_weights<<<dim3(512, 4), 128, 0, stream>>>(kw, kb, qw, qb, vw, vb, a_rel, m_rel,
                                                 p_rel, ow, ob, WT, bQKV, OWT, bO);
  init_kernel<<<(NT * Cc + 255) / 256, 256, 0, stream>>>(user_emb, movie_emb, phi,
                                                         meta_w, meta_b, xout, Xb, NU, NM);

  int NBU = (NU + 127) / 128;
  int NBM = (NM + 127) / 128;
  dim3 ggrid(NBU + NBM);
  for (int l = 0; l < Ll; ++l) {
    mfma_gemm<6, 0><<<ggrid, 256, 0, stream>>>(
        NBU, NU, NM, (const bf16*)Xb, (const bf16*)(WT + (size_t)l * 2 * 384 * Cc),
        bQKV + (size_t)l * 2 * 384, Qc, KVc, nullptr, nullptr, nullptr);
    agg_kernel<<<(NT + 3) / 4, 256, 0, stream>>>(rowptr, srcAll, Qc, KVc, AGGb, NM, NU);
    mfma_gemm<2, 1><<<ggrid, 256, 0, stream>>>(
        NBU, NU, NM, (const bf16*)AGGb, (const bf16*)(OWT + (size_t)l * 2 * Cc * Cc),
        bO + (size_t)l * 2 * Cc, nullptr, nullptr, xout, Xb, skip + (size_t)l * 2);
  }
}

// Round 7
// 395.818 us; speedup vs baseline: 2.5409x; 1.0227x over previous
//
#include <hip/hip_runtime.h>
#include <hip/hip_bf16.h>

#define Cc 128
#define Hh 4
#define Dd 32
#define DPHI2 64
#define Ll 2
#define Tt 2
#define Rr 2

typedef __hip_bfloat16 bf16;
using short8 = __attribute__((ext_vector_type(8))) short;
using f32x4 = __attribute__((ext_vector_type(4))) float;
using f32x2 = __attribute__((ext_vector_type(2))) float;
typedef _Float16 h2 __attribute__((ext_vector_type(2)));
typedef __fp16 fp16x2 __attribute__((ext_vector_type(2)));

__device__ __forceinline__ unsigned short f2bf(float f) {
  union { float f; unsigned u; } v; v.f = f;
  unsigned r = v.u + 0x7fff + ((v.u >> 16) & 1);
  return (unsigned short)(r >> 16);
}
__device__ __forceinline__ h2 u2h(unsigned u) {
  union { unsigned u; h2 h; } v; v.u = u; return v.h;
}
__device__ __forceinline__ unsigned pkh(float a, float b) {
  union { unsigned u; fp16x2 h; } v;
  v.h = __builtin_amdgcn_cvt_pkrtz(a, b);
  return v.u;
}

// ---- fp8 e4m3 helpers (HW cvt on gfx950; guarded fallbacks) ----
__device__ __forceinline__ float fp8_decode1(unsigned char b) {
  unsigned u = b & 0x7f;
  float nrm = __builtin_bit_cast(float, (u << 20) + 0x3C000000u);
  float sub = (float)u * 0.001953125f;
  float v = (u >= 8) ? nrm : sub;
  return (b & 0x80) ? -v : v;
}
template <bool HI>
__device__ __forceinline__ f32x2 fp8x2f(unsigned w) {
#if __has_builtin(__builtin_amdgcn_cvt_pk_f32_fp8)
  return __builtin_amdgcn_cvt_pk_f32_fp8(w, HI);
#else
  unsigned b = HI ? (w >> 16) : (w & 0xffff);
  f32x2 r;
  r[0] = fp8_decode1((unsigned char)b);
  r[1] = fp8_decode1((unsigned char)(b >> 8));
  return r;
#endif
}
#if !__has_builtin(__builtin_amdgcn_cvt_pk_fp8_f32)
__device__ __forceinline__ unsigned char fp8_encode1(float f) {
  unsigned s = (__builtin_bit_cast(unsigned, f) >> 31) << 7;
  float a = fabsf(f);
  a = fminf(a, 448.f);
  unsigned char out;
  if (a < 0.0009765625f) {
    out = 0;
  } else if (a < 0.015625f) {
    out = (unsigned char)(a * 512.f + 0.5f);
  } else {
    unsigned bits = __builtin_bit_cast(unsigned, a);
    int e = (int)(bits >> 23) - 127;
    unsigned m = (bits >> 20) & 7;
    m += (bits >> 19) & 1;
    unsigned ee = (unsigned)(e + 7);
    if (m == 8) { m = 0; ee += 1; }
    if (ee > 15) { ee = 15; m = 6; }
    out = (unsigned char)((ee << 3) | m);
  }
  return out | (unsigned char)s;
}
#endif
__device__ __forceinline__ unsigned pk_fp8x4(float v0, float v1, float v2, float v3) {
#if __has_builtin(__builtin_amdgcn_cvt_pk_fp8_f32)
  int p = __builtin_amdgcn_cvt_pk_fp8_f32(v0, v1, 0, false);
  p = __builtin_amdgcn_cvt_pk_fp8_f32(v2, v3, p, true);
  return (unsigned)p;
#else
  return (unsigned)fp8_encode1(v0) | ((unsigned)fp8_encode1(v1) << 8) |
         ((unsigned)fp8_encode1(v2) << 16) | ((unsigned)fp8_encode1(v3) << 24);
#endif
}

// ---- DPP quad reduce (xor1, xor2 within each 4-lane quad) ----
__device__ __forceinline__ float dpp_add_xor1(float x) {
  int v = __builtin_amdgcn_update_dpp(0, __builtin_bit_cast(int, x), 0xB1, 0xF, 0xF, true);
  return x + __builtin_bit_cast(float, v);
}
__device__ __forceinline__ float dpp_add_xor2(float x) {
  int v = __builtin_amdgcn_update_dpp(0, __builtin_bit_cast(int, x), 0x4E, 0xF, 0xF, true);
  return x + __builtin_bit_cast(float, v);
}

__device__ __forceinline__ float gelu_tanh(float x) {
  float u = 0.7978845608028654f * (x + 0.044715f * x * x * x);
  float t = 1.f - 2.f / (__expf(2.f * u) + 1.f);  // tanh(u)
  return 0.5f * x * (1.f + t);
}

// ---------------- CSR build (contiguous: movies [0,NM) then users [NM,NM+NU)) ----
__global__ void hist_kernel(const int* __restrict__ src, const int* __restrict__ dst,
                            int E_, int NM_, int* cnt) {
  int e = blockIdx.x * 256 + threadIdx.x;
  if (e < E_) {
    atomicAdd(&cnt[dst[e]], 1);
    atomicAdd(&cnt[NM_ + src[e]], 1);
  }
}

// 3-phase parallel scan: 1024 elems per block
__global__ __launch_bounds__(256) void scan_p1(const int* __restrict__ cnt, int n,
                                               int* __restrict__ psum) {
  int i0 = blockIdx.x * 1024 + threadIdx.x * 4;
  int s = 0;
#pragma unroll
  for (int j = 0; j < 4; ++j) {
    int i = i0 + j;
    if (i < n) s += cnt[i];
  }
#pragma unroll
  for (int off = 1; off < 64; off <<= 1) s += __shfl_xor(s, off, 64);
  __shared__ int wsum[4];
  if ((threadIdx.x & 63) == 0) wsum[threadIdx.x >> 6] = s;
  __syncthreads();
  if (threadIdx.x == 0) psum[blockIdx.x] = wsum[0] + wsum[1] + wsum[2] + wsum[3];
}
__global__ void scan_p2(int* psum, int nb) {
  if (threadIdx.x == 0 && blockIdx.x == 0) {
    int run = 0;
    for (int i = 0; i < nb; ++i) { int v = psum[i]; psum[i] = run; run += v; }
  }
}
__global__ __launch_bounds__(256) void scan_p3(const int* __restrict__ cnt, int n,
                                               const int* __restrict__ psum,
                                               int* __restrict__ rowptr) {
  __shared__ int sdata[256];
  int i0 = blockIdx.x * 1024 + threadIdx.x * 4;
  int a0 = (i0 + 0 < n) ? cnt[i0 + 0] : 0;
  int a1 = (i0 + 1 < n) ? cnt[i0 + 1] : 0;
  int a2 = (i0 + 2 < n) ? cnt[i0 + 2] : 0;
  int a3 = (i0 + 3 < n) ? cnt[i0 + 3] : 0;
  int s = a0 + a1 + a2 + a3;
  sdata[threadIdx.x] = s;
  __syncthreads();
  for (int off = 1; off < 256; off <<= 1) {
    int t = ((int)threadIdx.x >= off) ? sdata[threadIdx.x - off] : 0;
    __syncthreads();
    sdata[threadIdx.x] += t;
    __syncthreads();
  }
  int run = psum[blockIdx.x] + sdata[threadIdx.x] - s;
  if (i0 + 0 < n) rowptr[i0 + 1] = run + a0;
  if (i0 + 1 < n) rowptr[i0 + 2] = run + a0 + a1;
  if (i0 + 2 < n) rowptr[i0 + 3] = run + a0 + a1 + a2;
  if (i0 + 3 < n) rowptr[i0 + 4] = run + s;
  if (blockIdx.x == 0 && threadIdx.x == 0) rowptr[0] = 0;
}

// srcAll holds BYTE offsets into KVc (global_row * 256)
__global__ void scatter_kernel(const int* __restrict__ src, const int* __restrict__ dst, int E_,
                               const int* __restrict__ rowptr, int* cnt,
                               int* __restrict__ srcAll, int NU_, int NM_) {
  int e = blockIdx.x * 256 + threadIdx.x;
  if (e < E_) {
    int s = src[e], d = dst[e];
    int pm = rowptr[d] + atomicAdd(&cnt[d], 1);
    srcAll[pm] = s << 8;                    // user global row * 256
    int pu = rowptr[NM_ + s] + atomicAdd(&cnt[NM_ + s], 1);
    srcAll[pu] = (NU_ + d) << 8;            // movie global row * 256
  }
}

// ---------------- weight prep ----------------
// WT[lt][384][128] bf16: fused [qw*log2e/256 | kw@a_rel*p/sqrtD*256 | vw@m_rel*256]
__global__ __launch_bounds__(128) void prep_weights(
    const float* __restrict__ kw, const float* __restrict__ kb,
    const float* __restrict__ qw, const float* __restrict__ qb,
    const float* __restrict__ vw, const float* __restrict__ vb,
    const float* __restrict__ a_rel, const float* __restrict__ m_rel,
    const float* __restrict__ p_rel, const float* __restrict__ ow,
    const float* __restrict__ ob,
    unsigned short* __restrict__ WT, float* __restrict__ bQKV,
    unsigned short* __restrict__ OWT, float* __restrict__ bO) {
  int g = blockIdx.x;   // 0..511
  int lt = blockIdx.y;  // 0..3
  int l = lt >> 1, t = lt & 1, r = t;
  int k = threadIdx.x;
  const float inv_sqrt_d = 0.17677669529663687f;
  const float QSCALE = 1.4426950408889634f / 256.f;  // log2e / S_k
  const float KSCALE = 256.f;                        // S_k
  const float VSCALE = 256.f;                        // S_v
  float val, bval;
  if (g < 128) {
    val = qw[((size_t)lt * Cc + k) * Cc + g] * QSCALE;
    bval = qb[(size_t)lt * Cc + g] * QSCALE;
  } else if (g < 384) {
    int isV = (g >= 256);
    int n = g - (isV ? 256 : 128);
    int h = n >> 5, e = n & 31;
    const float* W = (isV ? vw : kw) + (size_t)lt * Cc * Cc;
    const float* bb = (isV ? vb : kb) + (size_t)lt * Cc;
    const float* Ah = (isV ? m_rel : a_rel) + (((size_t)l * Rr + r) * Hh + h) * Dd * Dd;
    float s = 0.f, sb = 0.f;
    for (int d = 0; d < Dd; ++d) {
      float ae = Ah[d * Dd + e];
      s += W[(size_t)k * Cc + h * Dd + d] * ae;
      sb += bb[h * Dd + d] * ae;
    }
    float scale = isV ? VSCALE : p_rel[((size_t)l * Rr + r) * Hh + h] * inv_sqrt_d * KSCALE;
    val = s * scale;
    bval = sb * scale;
  } else {
    int n = g - 384;
    val = ow[((size_t)lt * Cc + k) * Cc + n];
    bval = ob[(size_t)lt * Cc + n];
  }
  if (g < 384) {
    WT[((size_t)lt * 384 + g) * Cc + k] = f2bf(val);
    if (k == 0) bQKV[(size_t)lt * 384 + g] = bval;
  } else {
    OWT[((size_t)lt * Cc + (g - 384)) * Cc + k] = f2bf(val);
    if (k == 0) bO[(size_t)lt * Cc + (g - 384)] = bval;
  }
}

// ---------------- init: xout (f32) + Xb (bf16) ----------------
__global__ void init_kernel(const float* __restrict__ ue, const float* __restrict__ me,
                            const float* __restrict__ phi, const float* __restrict__ mw,
                            const float* __restrict__ mb,
                            float* __restrict__ xout, unsigned short* __restrict__ Xb,
                            int NU_, int NM_) {
  int i = blockIdx.x * 256 + threadIdx.x;
  int totalU = NU_ * Cc;
  if (i < totalU) {
    float v = ue[i];
    xout[i] = v;
    Xb[i] = f2bf(v);
  } else {
    int j = i - totalU;
    if (j >= NM_ * Cc) return;
    int m = j >> 7, c = j & 127;
    float s = me[j] + mb[c];
    const float* ph = phi + (size_t)m * DPHI2;
    for (int d = 0; d < DPHI2; ++d) s += ph[d] * mw[d * Cc + c];
    xout[i] = s;
    Xb[i] = f2bf(s);
  }
}

// ---------------- register-only MFMA GEMM, swapped operands (C^T layout) --------
// blocks [0,NBU) = users, rest = movies. 32 rows/wave, 128 rows/block.
// MODE 0: QKV proj. Q cols [0,128) -> Qc f16 (256B rows).
//   KE cols [128,256) / VE cols [256,384) -> KVc fp8 rows of 256B:
//   octet o (channels 8o..8o+7): K fp8 x8 at o*16, V fp8 x8 at o*16+8.
// MODE 1: out proj + skip-mix -> xout (f32) + Xb (bf16)
template <int NCH, int MODE>
__global__ __launch_bounds__(256, 2) void mfma_gemm(
    int NBU_, int NU_, int NM_,
    const bf16* __restrict__ Abase,
    const bf16* __restrict__ WTl, const float* __restrict__ biasl,
    char* __restrict__ Qc, char* __restrict__ KVc,
    float* __restrict__ xout, unsigned short* __restrict__ Xb,
    const float* __restrict__ skipl) {
  int bx = blockIdx.x;
  int t, row0, M, base;
  if (bx < NBU_) { t = 0; row0 = bx * 128; M = NU_; base = 0; }
  else { t = 1; row0 = (bx - NBU_) * 128; M = NM_; base = NU_; }
  const bf16* BT = WTl + (size_t)t * (NCH * 64) * Cc;
  const float* bias = biasl + (size_t)t * (NCH * 64);
  int wid = threadIdx.x >> 6, lane = threadIdx.x & 63;
  int rw = row0 + wid * 32;
  if (rw >= M) return;
  int lr = lane & 15, lk8 = (lane >> 4) * 8;
  short8 a[2][4];
#pragma unroll
  for (int mt = 0; mt < 2; ++mt) {
    int r = rw + mt * 16 + lr;
    const bf16* ap = Abase + (size_t)(base + r) * Cc + lk8;
#pragma unroll
    for (int kk = 0; kk < 4; ++kk) {
      short8 v = {};
      if (r < M) v = *(const short8*)(ap + kk * 32);
      a[mt][kk] = v;
    }
  }
  float g = 0.f;
  if (MODE == 1) g = 1.f / (1.f + __expf(-skipl[t]));
#pragma unroll
  for (int ch = 0; ch < NCH; ++ch) {
    short8 b[4][4];
#pragma unroll
    for (int nt = 0; nt < 4; ++nt) {
      const bf16* bp = BT + (size_t)(ch * 64 + nt * 16 + lr) * Cc + lk8;
#pragma unroll
      for (int kk = 0; kk < 4; ++kk) b[nt][kk] = *(const short8*)(bp + kk * 32);
    }
    f32x4 acc[2][4];
#pragma unroll
    for (int mt = 0; mt < 2; ++mt)
#pragma unroll
      for (int nt = 0; nt < 4; ++nt) acc[mt][nt] = (f32x4){0.f, 0.f, 0.f, 0.f};
#pragma unroll
    for (int kk = 0; kk < 4; ++kk)
#pragma unroll
      for (int mt = 0; mt < 2; ++mt)
#pragma unroll
        for (int nt = 0; nt < 4; ++nt)
          acc[mt][nt] = __builtin_amdgcn_mfma_f32_16x16x32_bf16(
              b[nt][kk], a[mt][kk], acc[mt][nt], 0, 0, 0);  // C^T: lane = 1 row, 4 cols
#pragma unroll
    for (int mt = 0; mt < 2; ++mt) {
      int r = rw + mt * 16 + lr;
      if (r >= M) continue;
      size_t grow = (size_t)(base + r);
#pragma unroll
      for (int nt = 0; nt < 4; ++nt) {
        int cb = ch * 64 + nt * 16 + 4 * (lane >> 4);
        float4 b4 = *(const float4*)&bias[cb];
        float v0 = acc[mt][nt][0] + b4.x;
        float v1 = acc[mt][nt][1] + b4.y;
        float v2 = acc[mt][nt][2] + b4.z;
        float v3 = acc[mt][nt][3] + b4.w;
        if (MODE == 0) {
          if (cb < Cc) {
            uint2 pk;
            pk.x = pkh(v0, v1); pk.y = pkh(v2, v3);
            *(uint2*)(Qc + grow * 256 + cb * 2) = pk;
          } else {
            int c = cb - 128;          // 0..255: [0,128)=K, [128,256)=V
            int isv = c >> 7; c &= 127;
            int off = (c >> 3) * 16 + (c & 7) + isv * 8;
            unsigned pk = pk_fp8x4(v0, v1, v2, v3);
            *(unsigned*)(KVc + grow * 256 + off) = pk;
          }
        } else {
          float* xp = xout + grow * Cc + cb;
          float4 old = *(const float4*)xp;
          float n0 = g * v0 + (1.f - g) * old.x;
          float n1 = g * v1 + (1.f - g) * old.y;
          float n2 = g * v2 + (1.f - g) * old.z;
          float n3 = g * v3 + (1.f - g) * old.w;
          *(float4*)xp = make_float4(n0, n1, n2, n3);
          uint2 pk;
          pk.x = (unsigned)f2bf(n0) | ((unsigned)f2bf(n1) << 16);
          pk.y = (unsigned)f2bf(n2) | ((unsigned)f2bf(n3) << 16);
          *(uint2*)(Xb + grow * Cc + cb) = pk;
        }
      }
    }
  }
}

// ---------------- fused softmax+agg: 1 wave/dst, quarter-wave/edge ---------
// Lane (eo=lane>>4, sub=lane&15): edge slot eo, channel octet sub (8 channels).
// One dwordx4/edge-lane: [K fp8 x8 | V fp8 x8]. Head h = sub>>2 -> the 4-lane
// quad reduce (DPP xor1,xor2) completes the 32-ch logit. w = exp2(p) (log2e and
// 1/sqrtD/p_rel/scales folded into weights). Cross-edge combine: shfl_xor 16,32.
__global__ __launch_bounds__(256) void agg_kernel(
    const int* __restrict__ rowptr, const int* __restrict__ srcAll,
    const char* __restrict__ Qc, const char* __restrict__ KVc,
    unsigned short* __restrict__ AGGb, int NM_, int NU_) {
  int wid = threadIdx.x >> 6, lane = threadIdx.x & 63;
  int W = blockIdx.x * 4 + wid;
  int dnode, beg, end;
  if (W < NM_) {
    dnode = NU_ + W; beg = rowptr[W]; end = rowptr[W + 1];
  } else {
    int u = W - NM_;
    if (u >= NU_) return;
    dnode = u; beg = rowptr[NM_ + u]; end = rowptr[NM_ + u + 1];
  }
  int sub = lane & 15, eo = lane >> 4;
  int myoff = sub * 16;
  uint4 qv = *(const uint4*)(Qc + (size_t)dnode * 256 + myoff);
  float qf0, qf1, qf2, qf3, qf4, qf5, qf6, qf7;
  {
    h2 t0 = u2h(qv.x), t1 = u2h(qv.y), t2 = u2h(qv.z), t3 = u2h(qv.w);
    qf0 = (float)t0[0]; qf1 = (float)t0[1];
    qf2 = (float)t1[0]; qf3 = (float)t1[1];
    qf4 = (float)t2[0]; qf5 = (float)t2[1];
    qf6 = (float)t3[0]; qf7 = (float)t3[1];
  }
  float acc0 = 0.f, acc1 = 0.f, acc2 = 0.f, acc3 = 0.f;
  float acc4 = 0.f, acc5 = 0.f, acc6 = 0.f, acc7 = 0.f;
  float denom = 0.f;

#define EDGE(E0)                                                                  \
  {                                                                               \
    int ei = (E0) + eo;                                                           \
    bool valid = ei < end;                                                        \
    int ec = valid ? ei : (end - 1);                                              \
    int so = srcAll[ec];                                                          \
    uint4 kv = *(const uint4*)(KVc + (size_t)(unsigned)so + myoff);               \
    f32x2 k01 = fp8x2f<false>(kv.x), k23 = fp8x2f<true>(kv.x);                    \
    f32x2 k45 = fp8x2f<false>(kv.y), k67 = fp8x2f<true>(kv.y);                    \
    float pA = qf0 * k01[0] + qf1 * k01[1] + qf2 * k23[0] + qf3 * k23[1];         \
    float pB = qf4 * k45[0] + qf5 * k45[1] + qf6 * k67[0] + qf7 * k67[1];         \
    float p = pA + pB;                                                            \
    p = dpp_add_xor1(p);                                                          \
    p = dpp_add_xor2(p);                                                          \
    float w = valid ? exp2f(p) : 0.f;                                             \
    denom += w;                                                                   \
    f32x2 v01 = fp8x2f<false>(kv.z), v23 = fp8x2f<true>(kv.z);                    \
    f32x2 v45 = fp8x2f<false>(kv.w), v67 = fp8x2f<true>(kv.w);                    \
    acc0 += w * v01[0]; acc1 += w * v01[1];                                       \
    acc2 += w * v23[0]; acc3 += w * v23[1];                                       \
    acc4 += w * v45[0]; acc5 += w * v45[1];                                       \
    acc6 += w * v67[0]; acc7 += w * v67[1];                                       \
  }

  for (int e0 = beg; e0 < end; e0 += 8) {
    EDGE(e0)
    EDGE(e0 + 4)
  }
#undef EDGE

  // combine the 4 edge slots (lanes differing in bits 4,5)
  denom += __shfl_xor(denom, 16, 64); denom += __shfl_xor(denom, 32, 64);
  acc0 += __shfl_xor(acc0, 16, 64); acc0 += __shfl_xor(acc0, 32, 64);
  acc1 += __shfl_xor(acc1, 16, 64); acc1 += __shfl_xor(acc1, 32, 64);
  acc2 += __shfl_xor(acc2, 16, 64); acc2 += __shfl_xor(acc2, 32, 64);
  acc3 += __shfl_xor(acc3, 16, 64); acc3 += __shfl_xor(acc3, 32, 64);
  acc4 += __shfl_xor(acc4, 16, 64); acc4 += __shfl_xor(acc4, 32, 64);
  acc5 += __shfl_xor(acc5, 16, 64); acc5 += __shfl_xor(acc5, 32, 64);
  acc6 += __shfl_xor(acc6, 16, 64); acc6 += __shfl_xor(acc6, 32, 64);
  acc7 += __shfl_xor(acc7, 16, 64); acc7 += __shfl_xor(acc7, 32, 64);

  if (lane < 16) {
    float inv = 1.f / (denom + 1e-16f) * 0.00390625f;  // /256 V scale
    float o0 = gelu_tanh(acc0 * inv);
    float o1 = gelu_tanh(acc1 * inv);
    float o2 = gelu_tanh(acc2 * inv);
    float o3 = gelu_tanh(acc3 * inv);
    float o4 = gelu_tanh(acc4 * inv);
    float o5 = gelu_tanh(acc5 * inv);
    float o6 = gelu_tanh(acc6 * inv);
    float o7 = gelu_tanh(acc7 * inv);
    uint4 pk;
    pk.x = (unsigned)f2bf(o0) | ((unsigned)f2bf(o1) << 16);
    pk.y = (unsigned)f2bf(o2) | ((unsigned)f2bf(o3) << 16);
    pk.z = (unsigned)f2bf(o4) | ((unsigned)f2bf(o5) << 16);
    pk.w = (unsigned)f2bf(o6) | ((unsigned)f2bf(o7) << 16);
    *(uint4*)(AGGb + (size_t)dnode * Cc + sub * 8) = pk;
  }
}

// ---------------- launch ----------------
extern "C" void kernel_launch(void* const* d_in, const int* in_sizes, int n_in,
                              void* d_out, int out_size, void* d_ws, size_t ws_size,
                              hipStream_t stream) {
  const float* user_emb = (const float*)d_in[0];
  const float* movie_emb = (const float*)d_in[1];
  const float* phi = (const float*)d_in[2];
  const float* meta_w = (const float*)d_in[3];
  const float* meta_b = (const float*)d_in[4];
  const float* kw = (const float*)d_in[5];
  const float* kb = (const float*)d_in[6];
  const float* qw = (const float*)d_in[7];
  const float* qb = (const float*)d_in[8];
  const float* vw = (const float*)d_in[9];
  const float* vb = (const float*)d_in[10];
  const float* a_rel = (const float*)d_in[11];
  const float* m_rel = (const float*)d_in[12];
  const float* p_rel = (const float*)d_in[13];
  const float* ow = (const float*)d_in[14];
  const float* ob = (const float*)d_in[15];
  const float* skip = (const float*)d_in[16];
  const int* eidx = (const int*)d_in[17];

  int NU = in_sizes[0] / Cc;
  int NM = in_sizes[1] / Cc;
  int E_ = in_sizes[17] / 2;
  int NT = NU + NM;
  const int* esrc = eidx;
  const int* edst = eidx + E_;

  char* ws = (char*)d_ws;
  size_t off = 0;
  auto alloc = [&](size_t bytes) -> char* {
    char* p = ws + off;
    off = (off + bytes + 255) & ~(size_t)255;
    return p;
  };
  char* Qc = alloc((size_t)NT * 256);
  char* KVc = alloc((size_t)NT * 256);
  unsigned short* Xb = (unsigned short*)alloc((size_t)NT * Cc * 2);
  unsigned short* AGGb = (unsigned short*)alloc((size_t)NT * Cc * 2);
  unsigned short* WT = (unsigned short*)alloc((size_t)Ll * Tt * 384 * Cc * 2);
  unsigned short* OWT = (unsigned short*)alloc((size_t)Ll * Tt * Cc * Cc * 2);
  float* bQKV = (float*)alloc((size_t)Ll * Tt * 384 * 4);
  float* bO = (float*)alloc((size_t)Ll * Tt * Cc * 4);
  int* rowptr = (int*)alloc((size_t)(NT + 1) * 4);
  int* srcAll = (int*)alloc((size_t)2 * E_ * 4);
  int* cnt = (int*)alloc((size_t)NT * 4);
  int* psum = (int*)alloc((size_t)256 * 4);
  float* xout = (float*)d_out;

  int nblk = (NT + 1023) / 1024;

  // CSR build (movies [0,NM), users [NM,NT))
  hipMemsetAsync(cnt, 0, (size_t)NT * 4, stream);
  hist_kernel<<<(E_ + 255) / 256, 256, 0, stream>>>(esrc, edst, E_, NM, cnt);
  scan_p1<<<nblk, 256, 0, stream>>>(cnt, NT, psum);
  scan_p2<<<1, 64, 0, stream>>>(psum, nblk);
  scan_p3<<<nblk, 256, 0, stream>>>(cnt, NT, psum, rowptr);
  hipMemsetAsync(cnt, 0, (size_t)NT * 4, stream);
  scatter_kernel<<<(E_ + 255) / 256, 256, 0, stream>>>(esrc, edst, E_, rowptr, cnt,
                                                       srcAll, NU, NM);

  prep_weights<<<dim3(512, 4), 128, 0, stream>>>(kw, kb, qw, qb, vw, vb, a_rel, m_rel,
                                                 p_rel, ow, ob, WT, bQKV, OWT, bO);
  init_kernel<<<(NT * Cc + 255) / 256, 256, 0, stream>>>(user_emb, movie_emb, phi,
                                                         meta_w, meta_b, xout, Xb, NU, NM);

  int NBU = (NU + 127) / 128;
  int NBM = (NM + 127) / 128;
  dim3 ggrid(NBU + NBM);
  for (int l = 0; l < Ll; ++l) {
    mfma_gemm<6, 0><<<ggrid, 256, 0, stream>>>(
        NBU, NU, NM, (const bf16*)Xb, (const bf16*)(WT + (size_t)l * 2 * 384 * Cc),
        bQKV + (size_t)l * 2 * 384, Qc, KVc, nullptr, nullptr, nullptr);
    agg_kernel<<<(NT + 3) / 4, 256, 0, stream>>>(rowptr, srcAll, Qc, KVc, AGGb, NM, NU);
    mfma_gemm<2, 1><<<ggrid, 256, 0, stream>>>(
        NBU, NU, NM, (const bf16*)AGGb, (const bf16*)(OWT + (size_t)l * 2 * Cc * Cc),
        bO + (size_t)l * 2 * Cc, nullptr, nullptr, xout, Xb, skip + (size_t)l * 2);
  }
}